// Round 4
// baseline (771.771 us; speedup 1.0000x reference)
//
#include <hip/hip_runtime.h>
#include <math.h>

#define S_DIM 1024
#define B_DIM 4
#define E_DIM 1024
#define H_DIM 16
#define M_DIM 128
#define V_DIM 64

typedef __attribute__((ext_vector_type(8))) short short8;
typedef __attribute__((ext_vector_type(4))) float f32x4;
typedef __attribute__((ext_vector_type(4))) int int4v;

__device__ __forceinline__ unsigned short f2bf(float f) {
    union { float f; unsigned u; } v; v.f = f;
    unsigned r = v.u + 0x7FFFu + ((v.u >> 16) & 1u);   // round-to-nearest-even
    return (unsigned short)(r >> 16);
}

__device__ __forceinline__ void async16(const unsigned short* g, unsigned short* l) {
    __builtin_amdgcn_global_load_lds(
        (const __attribute__((address_space(1))) void*)g,
        (__attribute__((address_space(3))) void*)l,
        16, 0, 0);
}

// ---------------- convert: fp32 (re,im) -> bf16 arrays ----------------
__global__ __launch_bounds__(256) void convert_pair(
    const float* __restrict__ re, const float* __restrict__ im,
    unsigned short* __restrict__ dre, unsigned short* __restrict__ dim_, int n4)
{
    int i = blockIdx.x * 256 + threadIdx.x;
    if (i >= n4) return;
    float4 r = ((const float4*)re)[i];
    float4 m = ((const float4*)im)[i];
    ushort4 ro, mo;
    ro.x = f2bf(r.x); ro.y = f2bf(r.y); ro.z = f2bf(r.z); ro.w = f2bf(r.w);
    mo.x = f2bf(m.x); mo.y = f2bf(m.y); mo.z = f2bf(m.z); mo.w = f2bf(m.w);
    ((ushort4*)dre)[i] = ro;
    ((ushort4*)dim_)[i] = mo;
}

// wo (e,f) -> woT (f,e) bf16
__global__ __launch_bounds__(256) void transpose_wo(
    const float* __restrict__ wore, const float* __restrict__ woim,
    unsigned short* __restrict__ wtre, unsigned short* __restrict__ wtim)
{
    __shared__ float tr[32][33], ti[32][33];
    const int bx = blockIdx.x * 32;   // e range
    const int by = blockIdx.y * 32;   // f range
    const int tx = threadIdx.x & 31, ty = threadIdx.x >> 5;
    for (int i = ty; i < 32; i += 8) {
        tr[i][tx] = wore[(bx + i) * E_DIM + by + tx];
        ti[i][tx] = woim[(bx + i) * E_DIM + by + tx];
    }
    __syncthreads();
    for (int i = ty; i < 32; i += 8) {
        wtre[(by + i) * E_DIM + bx + tx] = f2bf(tr[tx][i]);
        wtim[(by + i) * E_DIM + bx + tx] = f2bf(ti[tx][i]);
    }
}

// v planes [bh][t][64] -> v^T planes [bh][v][1024]
__global__ __launch_bounds__(256) void vtrans(
    const unsigned short* __restrict__ vrp, const unsigned short* __restrict__ vip,
    unsigned short* __restrict__ vrt, unsigned short* __restrict__ vit)
{
    __shared__ unsigned short tl[2][64][66];
    const int tid = threadIdx.x;
    const int t0 = blockIdx.x * 64;
    const int bh = blockIdx.y;
    #pragma unroll
    for (int pl = 0; pl < 2; ++pl) {
        const unsigned short* src = pl ? vip : vrp;
        #pragma unroll
        for (int p = 0; p < 2; ++p) {
            const int row = p * 32 + (tid >> 3);
            const int col = (tid & 7) * 8;
            short8 d = *(const short8*)&src[((size_t)bh * S_DIM + t0 + row) * V_DIM + col];
            #pragma unroll
            for (int j = 0; j < 8; ++j) tl[pl][row][col + j] = (unsigned short)d[j];
        }
    }
    __syncthreads();
    #pragma unroll
    for (int pl = 0; pl < 2; ++pl) {
        unsigned short* dst = pl ? vit : vrt;
        #pragma unroll
        for (int p = 0; p < 2; ++p) {
            const int v = p * 32 + (tid >> 3);
            const int tc = (tid & 7) * 8;
            short8 d;
            #pragma unroll
            for (int j = 0; j < 8; ++j) d[j] = (short)tl[pl][tc + j][v];
            *(short8*)&dst[((size_t)bh * V_DIM + v) * S_DIM + t0 + tc] = d;
        }
    }
}

// ---------------- complex bf16 MFMA GEMM: C = A * B^T ----------------
// MODE 0: Mr=4096 (s,b), Nc=5120 (q|k|v) -> bf16 planes qr/qi/kr/ki/vr/vi
// MODE 2: Mr=4096, Nc=1024, split-K x2 (blockIdx.z); atomicAdd into zeroed out,
//         residual x added by the z==0 half.
template<int MODE>
__global__ __launch_bounds__(256, 3) void cgemm(
    const unsigned short* __restrict__ Are, const unsigned short* __restrict__ Aim,
    const unsigned short* __restrict__ Bre, const unsigned short* __restrict__ Bim,
    unsigned short* __restrict__ qrp, unsigned short* __restrict__ qip,
    unsigned short* __restrict__ krp, unsigned short* __restrict__ kip,
    unsigned short* __restrict__ vrp, unsigned short* __restrict__ vip,
    const float* __restrict__ xre, const float* __restrict__ xim,
    float* __restrict__ out)
{
    __shared__ unsigned short lds[16384];  // 32 KB: Are|Aim|Bre|Bim tiles [128][32]
    const int tid  = threadIdx.x;
    const int wave = tid >> 6;
    const int lane = tid & 63;
    const int r0 = blockIdx.x * 128;
    const int j0 = blockIdx.y * 128;
    const int wm = (wave >> 1) * 64;
    const int wn = (wave & 1) * 64;

    f32x4 accre[4][4], accim[4][4];
    #pragma unroll
    for (int i = 0; i < 4; ++i)
        #pragma unroll
        for (int j = 0; j < 4; ++j) {
            accre[i][j] = (f32x4){0.f, 0.f, 0.f, 0.f};
            accim[i][j] = (f32x4){0.f, 0.f, 0.f, 0.f};
        }

    const int srow = lane >> 2;          // staging: 4 lanes per 64B row
    const int scol = (lane & 3) * 8;
    const int lrow = lane & 15;          // frag: m/n index
    const int lk   = (lane >> 4) * 8;    // frag: k offset

    const int kbeg = (MODE == 2) ? (int)blockIdx.z * (E_DIM / 2) : 0;
    const int kend = (MODE == 2) ? kbeg + (E_DIM / 2) : E_DIM;

    for (int k0 = kbeg; k0 < kend; k0 += 32) {
        __syncthreads();
        #pragma unroll
        for (int c = 0; c < 2; ++c) {
            const int ag = (r0 + c * 64 + wave * 16 + srow) * E_DIM + k0 + scol;
            const int bg = (j0 + c * 64 + wave * 16 + srow) * E_DIM + k0 + scol;
            const int lb = wave * 512 + c * 2048;  // ushort index within tile
            async16(Are + ag, &lds[lb]);
            async16(Aim + ag, &lds[4096 + lb]);
            async16(Bre + bg, &lds[8192 + lb]);
            async16(Bim + bg, &lds[12288 + lb]);
        }
        __syncthreads();

        short8 ar[4], ai[4], ain[4];
        #pragma unroll
        for (int im = 0; im < 4; ++im) {
            const int row = wm + im * 16 + lrow;
            ar[im] = *(const short8*)&lds[row * 32 + lk];
            ai[im] = *(const short8*)&lds[4096 + row * 32 + lk];
            int4v t = *(int4v*)&ai[im];
            t = t ^ (int)0x80008000;       // negate bf16 pair (sign-bit flip)
            ain[im] = *(short8*)&t;
        }
        #pragma unroll
        for (int jn = 0; jn < 4; ++jn) {
            const int row = wn + jn * 16 + lrow;
            const short8 br = *(const short8*)&lds[8192 + row * 32 + lk];
            const short8 bi = *(const short8*)&lds[12288 + row * 32 + lk];
            #pragma unroll
            for (int im = 0; im < 4; ++im) {
                accre[im][jn] = __builtin_amdgcn_mfma_f32_16x16x32_bf16(ar[im],  br, accre[im][jn], 0, 0, 0);
                accre[im][jn] = __builtin_amdgcn_mfma_f32_16x16x32_bf16(ain[im], bi, accre[im][jn], 0, 0, 0);
                accim[im][jn] = __builtin_amdgcn_mfma_f32_16x16x32_bf16(ar[im],  bi, accim[im][jn], 0, 0, 0);
                accim[im][jn] = __builtin_amdgcn_mfma_f32_16x16x32_bf16(ai[im],  br, accim[im][jn], 0, 0, 0);
            }
        }
    }

    // epilogue: D row = (lane>>4)*4+reg, col = lane&15  [measured m89/m91]
    #pragma unroll
    for (int im = 0; im < 4; ++im) {
        #pragma unroll
        for (int reg = 0; reg < 4; ++reg) {
            const int r = r0 + wm + im * 16 + (lane >> 4) * 4 + reg;
            #pragma unroll
            for (int jn = 0; jn < 4; ++jn) {
                const int j = j0 + wn + jn * 16 + (lane & 15);
                const float vr = accre[im][jn][reg];
                const float vi = accim[im][jn][reg];
                if (MODE == 0) {
                    const int s = r >> 2, b = r & 3;   // r = s*B + b
                    if (j < 2048) {
                        const int h = j >> 7, m = j & 127;
                        const size_t off = ((size_t)(b * H_DIM + h) * S_DIM + s) * M_DIM + m;
                        qrp[off] = f2bf(vr); qip[off] = f2bf(vi);
                    } else if (j < 4096) {
                        const int jl = j - 2048, h = jl >> 7, m = jl & 127;
                        const size_t off = ((size_t)(b * H_DIM + h) * S_DIM + s) * M_DIM + m;
                        krp[off] = f2bf(vr); kip[off] = f2bf(vi);
                    } else {
                        const int jl = j - 4096, h = jl >> 6, vv = jl & 63;
                        const size_t off = ((size_t)(b * H_DIM + h) * S_DIM + s) * V_DIM + vv;
                        vrp[off] = f2bf(vr); vip[off] = f2bf(vi);
                    }
                } else {
                    const int idx = r * E_DIM + j;
                    float addr_ = vr, addi_ = vi;
                    if (blockIdx.z == 0) { addr_ += xre[idx]; addi_ += xim[idx]; }
                    unsafeAtomicAdd(&out[idx], addr_);
                    unsafeAtomicAdd(&out[S_DIM * B_DIM * E_DIM + idx], addi_);
                }
            }
        }
    }
}

// ---------------- K2: MFMA flash attention ----------------
// block = one (b,h) x 64 q rows; 4 waves x 16 rows; K-tile 64.
// Staging is software-pipelined: next K/V tile is loaded into registers while
// the current tile is being consumed from LDS.
__global__ __launch_bounds__(256, 2) void attn_mfma(
    const unsigned short* __restrict__ qr, const unsigned short* __restrict__ qi,
    const unsigned short* __restrict__ kr, const unsigned short* __restrict__ ki,
    const unsigned short* __restrict__ vrt, const unsigned short* __restrict__ vit,
    unsigned short* __restrict__ updre, unsigned short* __restrict__ updim)
{
    __shared__ __align__(16) unsigned short Ks[2][64][136];  // K tile [plane][t][m] (Q staged here first)
    __shared__ __align__(16) unsigned short Vs[2][64][72];   // V^T tile [plane][v][t]
    __shared__ __align__(16) unsigned short Ps[4][16][72];   // per-wave P [q][t]

    const int tid  = threadIdx.x;
    const int wave = tid >> 6;
    const int lane = tid & 63;
    const int qt = (int)gridDim.x - 1 - blockIdx.x;  // long blocks launch first
    const int bh = blockIdx.y;
    const int q0 = qt * 64;
    const size_t base_qk = (size_t)bh * S_DIM * M_DIM;
    const size_t base_v  = (size_t)bh * V_DIM * S_DIM;

    const int fr = lane & 15;        // frag m/n index
    const int fg = lane >> 4;        // 0..3
    const int fk = fg * 8;           // frag k offset (bf16)

    // staging coords
    const int krow = tid >> 4, kcol = (tid & 15) * 8;   // K: 16 rows/pass
    const int vrow = tid >> 3, vcol = (tid & 7) * 8;    // V: 32 rows/pass

    // ---- stage Q tile into Ks, extract per-wave A-frags to registers ----
    #pragma unroll
    for (int pl = 0; pl < 2; ++pl) {
        const unsigned short* src = pl ? qi : qr;
        #pragma unroll
        for (int p = 0; p < 4; ++p)
            *(short8*)&Ks[pl][p * 16 + krow][kcol] =
                *(const short8*)&src[base_qk + (size_t)(q0 + p * 16 + krow) * M_DIM + kcol];
    }
    __syncthreads();
    short8 Aqr[4], Aqi[4], Aqin[4];
    {
        const int qrow = wave * 16 + fr;
        #pragma unroll
        for (int ks = 0; ks < 4; ++ks) {
            Aqr[ks] = *(const short8*)&Ks[0][qrow][ks * 32 + fk];
            Aqi[ks] = *(const short8*)&Ks[1][qrow][ks * 32 + fk];
            int4v t = *(int4v*)&Aqi[ks];
            t = t ^ (int)0x80008000;
            Aqin[ks] = *(short8*)&t;
        }
    }

    f32x4 Ore[4], Oim[4];
    #pragma unroll
    for (int vt = 0; vt < 4; ++vt) {
        Ore[vt] = (f32x4){0.f, 0.f, 0.f, 0.f};
        Oim[vt] = (f32x4){0.f, 0.f, 0.f, 0.f};
    }
    float mrun[4] = {-INFINITY, -INFINITY, -INFINITY, -INFINITY};
    float lrun[4] = {0.f, 0.f, 0.f, 0.f};

    const float scale = 0.088388347648318447f;  // 1/sqrt(128)
    const int qbase = q0 + wave * 16 + fg * 4;  // + reg = global q row

    // ---- prefetch tile t0=0 into registers ----
    short8 pk[2][4], pv[2][2];
    #pragma unroll
    for (int pl = 0; pl < 2; ++pl) {
        const unsigned short* src = pl ? ki : kr;
        #pragma unroll
        for (int p = 0; p < 4; ++p)
            pk[pl][p] = *(const short8*)&src[base_qk + (size_t)(p * 16 + krow) * M_DIM + kcol];
    }
    #pragma unroll
    for (int pl = 0; pl < 2; ++pl) {
        const unsigned short* src = pl ? vit : vrt;
        #pragma unroll
        for (int p = 0; p < 2; ++p)
            pv[pl][p] = *(const short8*)&src[base_v + (size_t)(p * 32 + vrow) * S_DIM + vcol];
    }

    for (int t0 = 0; t0 <= q0; t0 += 64) {
        __syncthreads();   // prior readers of Ks/Vs done (iter0: Q frags extracted)
        // ---- commit prefetched K/V tile to LDS ----
        #pragma unroll
        for (int pl = 0; pl < 2; ++pl) {
            #pragma unroll
            for (int p = 0; p < 4; ++p)
                *(short8*)&Ks[pl][p * 16 + krow][kcol] = pk[pl][p];
            #pragma unroll
            for (int p = 0; p < 2; ++p)
                *(short8*)&Vs[pl][p * 32 + vrow][vcol] = pv[pl][p];
        }
        __syncthreads();

        // ---- issue next tile's global loads (consumed next iteration) ----
        if (t0 + 64 <= q0) {
            const int tn = t0 + 64;
            #pragma unroll
            for (int pl = 0; pl < 2; ++pl) {
                const unsigned short* src = pl ? ki : kr;
                #pragma unroll
                for (int p = 0; p < 4; ++p)
                    pk[pl][p] = *(const short8*)&src[base_qk + (size_t)(tn + p * 16 + krow) * M_DIM + kcol];
            }
            #pragma unroll
            for (int pl = 0; pl < 2; ++pl) {
                const unsigned short* src = pl ? vit : vrt;
                #pragma unroll
                for (int p = 0; p < 2; ++p)
                    pv[pl][p] = *(const short8*)&src[base_v + (size_t)(p * 32 + vrow) * S_DIM + tn + vcol];
            }
        }

        // ---- QK^T (complex) into S fragments ----
        f32x4 Sre[4], Sim[4];
        #pragma unroll
        for (int tt = 0; tt < 4; ++tt) {
            Sre[tt] = (f32x4){0.f, 0.f, 0.f, 0.f};
            Sim[tt] = (f32x4){0.f, 0.f, 0.f, 0.f};
            const int trow = tt * 16 + fr;
            #pragma unroll
            for (int ks = 0; ks < 4; ++ks) {
                const short8 Bkr = *(const short8*)&Ks[0][trow][ks * 32 + fk];
                const short8 Bki = *(const short8*)&Ks[1][trow][ks * 32 + fk];
                Sre[tt] = __builtin_amdgcn_mfma_f32_16x16x32_bf16(Aqr[ks],  Bkr, Sre[tt], 0, 0, 0);
                Sre[tt] = __builtin_amdgcn_mfma_f32_16x16x32_bf16(Aqin[ks], Bki, Sre[tt], 0, 0, 0);
                Sim[tt] = __builtin_amdgcn_mfma_f32_16x16x32_bf16(Aqr[ks],  Bki, Sim[tt], 0, 0, 0);
                Sim[tt] = __builtin_amdgcn_mfma_f32_16x16x32_bf16(Aqi[ks],  Bkr, Sim[tt], 0, 0, 0);
            }
        }

        // ---- amplitude + causal mask + online softmax (register state) ----
        float amp[4][4];
        #pragma unroll
        for (int tt = 0; tt < 4; ++tt) {
            const int tg = t0 + tt * 16 + fr;
            #pragma unroll
            for (int r = 0; r < 4; ++r) {
                const float re = Sre[tt][r], im = Sim[tt][r];
                const float a = sqrtf(re * re + im * im) * scale;
                amp[tt][r] = (tg > qbase + r) ? -INFINITY : a;
            }
        }
        float al[4];
        #pragma unroll
        for (int r = 0; r < 4; ++r) {
            float rm = fmaxf(fmaxf(amp[0][r], amp[1][r]), fmaxf(amp[2][r], amp[3][r]));
            rm = fmaxf(rm, __shfl_xor(rm, 1));
            rm = fmaxf(rm, __shfl_xor(rm, 2));
            rm = fmaxf(rm, __shfl_xor(rm, 4));
            rm = fmaxf(rm, __shfl_xor(rm, 8));
            const float nm = fmaxf(mrun[r], rm);
            al[r] = __expf(mrun[r] - nm);
            mrun[r] = nm;
            float psum = 0.f;
            #pragma unroll
            for (int tt = 0; tt < 4; ++tt) {
                const float p = __expf(amp[tt][r] - nm);
                psum += p;
                Ps[wave][fg * 4 + r][tt * 16 + fr] = f2bf(p);
            }
            psum += __shfl_xor(psum, 1);
            psum += __shfl_xor(psum, 2);
            psum += __shfl_xor(psum, 4);
            psum += __shfl_xor(psum, 8);
            lrun[r] = lrun[r] * al[r] + psum;
        }
        #pragma unroll
        for (int vt = 0; vt < 4; ++vt)
            #pragma unroll
            for (int r = 0; r < 4; ++r) { Ore[vt][r] *= al[r]; Oim[vt][r] *= al[r]; }

        // ---- PV: P (A-layout via per-wave LDS) x V^T fragments ----
        short8 Pa0 = *(const short8*)&Ps[wave][fr][fk];
        short8 Pa1 = *(const short8*)&Ps[wave][fr][32 + fk];
        #pragma unroll
        for (int vt = 0; vt < 4; ++vt) {
            const int vr2 = vt * 16 + fr;
            short8 B0r = *(const short8*)&Vs[0][vr2][fk];
            short8 B1r = *(const short8*)&Vs[0][vr2][32 + fk];
            short8 B0i = *(const short8*)&Vs[1][vr2][fk];
            short8 B1i = *(const short8*)&Vs[1][vr2][32 + fk];
            Ore[vt] = __builtin_amdgcn_mfma_f32_16x16x32_bf16(Pa0, B0r, Ore[vt], 0, 0, 0);
            Ore[vt] = __builtin_amdgcn_mfma_f32_16x16x32_bf16(Pa1, B1r, Ore[vt], 0, 0, 0);
            Oim[vt] = __builtin_amdgcn_mfma_f32_16x16x32_bf16(Pa0, B0i, Oim[vt], 0, 0, 0);
            Oim[vt] = __builtin_amdgcn_mfma_f32_16x16x32_bf16(Pa1, B1i, Oim[vt], 0, 0, 0);
        }
    }

    // ---- epilogue ----
    const int b = bh >> 4, h = bh & 15;
    float inv[4];
    #pragma unroll
    for (int r = 0; r < 4; ++r) inv[r] = 1.0f / lrun[r];
    #pragma unroll
    for (int vt = 0; vt < 4; ++vt) {
        #pragma unroll
        for (int r = 0; r < 4; ++r) {
            const int s = qbase + r;
            const size_t off = ((size_t)(s * B_DIM + b)) * E_DIM + h * V_DIM + vt * 16 + fr;
            updre[off] = f2bf(Ore[vt][r] * inv[r]);
            updim[off] = f2bf(Oim[vt][r] * inv[r]);
        }
    }
}

extern "C" void kernel_launch(void* const* d_in, const int* in_sizes, int n_in,
                              void* d_out, int out_size, void* d_ws, size_t ws_size,
                              hipStream_t stream) {
    const float* xre  = (const float*)d_in[0];
    const float* xim  = (const float*)d_in[1];
    const float* wqre = (const float*)d_in[2];
    const float* wqim = (const float*)d_in[3];
    const float* wkre = (const float*)d_in[4];
    const float* wkim = (const float*)d_in[5];
    const float* wvre = (const float*)d_in[6];
    const float* wvim = (const float*)d_in[7];
    const float* wore = (const float*)d_in[8];
    const float* woim = (const float*)d_in[9];
    float* out = (float*)d_out;

    // workspace layout (~160 MB)
    char* p = (char*)d_ws;
    const size_t QK = (size_t)B_DIM * H_DIM * S_DIM * M_DIM;   // 8.39M
    const size_t VS = (size_t)B_DIM * H_DIM * S_DIM * V_DIM;   // 4.19M
    const size_t SBE = (size_t)S_DIM * B_DIM * E_DIM;          // 4.19M
    unsigned short* qrw = (unsigned short*)p;  p += QK * 2;
    unsigned short* qiw = (unsigned short*)p;  p += QK * 2;
    unsigned short* krw = (unsigned short*)p;  p += QK * 2;
    unsigned short* kiw = (unsigned short*)p;  p += QK * 2;
    unsigned short* vrw = (unsigned short*)p;  p += VS * 2;
    unsigned short* viw = (unsigned short*)p;  p += VS * 2;
    unsigned short* vrt = (unsigned short*)p;  p += VS * 2;
    unsigned short* vit = (unsigned short*)p;  p += VS * 2;
    unsigned short* updre = (unsigned short*)p; p += SBE * 2;
    unsigned short* updim = (unsigned short*)p; p += SBE * 2;
    unsigned short* xbre  = (unsigned short*)p; p += SBE * 2;
    unsigned short* xbim  = (unsigned short*)p; p += SBE * 2;
    unsigned short* wbre  = (unsigned short*)p; p += (size_t)5120 * E_DIM * 2;
    unsigned short* wbim  = (unsigned short*)p; p += (size_t)5120 * E_DIM * 2;
    unsigned short* wtre  = (unsigned short*)p; p += (size_t)E_DIM * E_DIM * 2;
    unsigned short* wtim  = (unsigned short*)p; p += (size_t)E_DIM * E_DIM * 2;

    // bf16 conversion passes
    convert_pair<<<4096, 256, 0, stream>>>(xre, xim, xbre, xbim, 1048576);
    convert_pair<<<2048, 256, 0, stream>>>(wqre, wqim, wbre, wbim, 524288);
    convert_pair<<<2048, 256, 0, stream>>>(wkre, wkim, wbre + 2048*1024, wbim + 2048*1024, 524288);
    convert_pair<<<1024, 256, 0, stream>>>(wvre, wvim, wbre + 4096*1024, wbim + 4096*1024, 262144);
    transpose_wo<<<dim3(32, 32), 256, 0, stream>>>(wore, woim, wtre, wtim);

    // QKV projection (bf16 MFMA) -> separated planes
    cgemm<0><<<dim3(32, 40), 256, 0, stream>>>(xbre, xbim, wbre, wbim,
                                               qrw, qiw, krw, kiw, vrw, viw,
                                               nullptr, nullptr, nullptr);
    // V -> V^T planes
    vtrans<<<dim3(16, 64), 256, 0, stream>>>(vrw, viw, vrt, vit);
    // MFMA flash attention
    attn_mfma<<<dim3(16, 64), 256, 0, stream>>>(qrw, qiw, krw, kiw, vrt, vit, updre, updim);
    // output projection + residual: zero-init out, then split-K x2 atomic accumulate
    hipMemsetAsync(out, 0, (size_t)2 * SBE * sizeof(float), stream);
    cgemm<2><<<dim3(32, 8, 2), 256, 0, stream>>>(updre, updim, wtre, wtim,
                                                 nullptr, nullptr, nullptr, nullptr, nullptr, nullptr,
                                                 xre, xim, out);
}

// Round 5
// 649.091 us; speedup vs baseline: 1.1890x; 1.1890x over previous
//
#include <hip/hip_runtime.h>
#include <math.h>

#define S_DIM 1024
#define B_DIM 4
#define E_DIM 1024
#define H_DIM 16
#define M_DIM 128
#define V_DIM 64

typedef __attribute__((ext_vector_type(8))) short short8;
typedef __attribute__((ext_vector_type(4))) float f32x4;
typedef __attribute__((ext_vector_type(4))) int int4v;

__device__ __forceinline__ unsigned short f2bf(float f) {
    union { float f; unsigned u; } v; v.f = f;
    unsigned r = v.u + 0x7FFFu + ((v.u >> 16) & 1u);   // round-to-nearest-even
    return (unsigned short)(r >> 16);
}

__device__ __forceinline__ void async16(const unsigned short* g, unsigned short* l) {
    __builtin_amdgcn_global_load_lds(
        (const __attribute__((address_space(1))) void*)g,
        (__attribute__((address_space(3))) void*)l,
        16, 0, 0);
}

// ---------------- convert: fp32 (re,im) -> bf16 arrays ----------------
__global__ __launch_bounds__(256) void convert_pair(
    const float* __restrict__ re, const float* __restrict__ im,
    unsigned short* __restrict__ dre, unsigned short* __restrict__ dim_, int n4)
{
    int i = blockIdx.x * 256 + threadIdx.x;
    if (i >= n4) return;
    float4 r = ((const float4*)re)[i];
    float4 m = ((const float4*)im)[i];
    ushort4 ro, mo;
    ro.x = f2bf(r.x); ro.y = f2bf(r.y); ro.z = f2bf(r.z); ro.w = f2bf(r.w);
    mo.x = f2bf(m.x); mo.y = f2bf(m.y); mo.z = f2bf(m.z); mo.w = f2bf(m.w);
    ((ushort4*)dre)[i] = ro;
    ((ushort4*)dim_)[i] = mo;
}

// wo (e,f) -> woT (f,e) bf16
__global__ __launch_bounds__(256) void transpose_wo(
    const float* __restrict__ wore, const float* __restrict__ woim,
    unsigned short* __restrict__ wtre, unsigned short* __restrict__ wtim)
{
    __shared__ float tr[32][33], ti[32][33];
    const int bx = blockIdx.x * 32;   // e range
    const int by = blockIdx.y * 32;   // f range
    const int tx = threadIdx.x & 31, ty = threadIdx.x >> 5;
    for (int i = ty; i < 32; i += 8) {
        tr[i][tx] = wore[(bx + i) * E_DIM + by + tx];
        ti[i][tx] = woim[(bx + i) * E_DIM + by + tx];
    }
    __syncthreads();
    for (int i = ty; i < 32; i += 8) {
        wtre[(by + i) * E_DIM + bx + tx] = f2bf(tr[tx][i]);
        wtim[(by + i) * E_DIM + bx + tx] = f2bf(ti[tx][i]);
    }
}

// v planes [bh][t][64] -> v^T planes [bh][v][1024]
__global__ __launch_bounds__(256) void vtrans(
    const unsigned short* __restrict__ vrp, const unsigned short* __restrict__ vip,
    unsigned short* __restrict__ vrt, unsigned short* __restrict__ vit)
{
    __shared__ unsigned short tl[2][64][66];
    const int tid = threadIdx.x;
    const int t0 = blockIdx.x * 64;
    const int bh = blockIdx.y;
    #pragma unroll
    for (int pl = 0; pl < 2; ++pl) {
        const unsigned short* src = pl ? vip : vrp;
        #pragma unroll
        for (int p = 0; p < 2; ++p) {
            const int row = p * 32 + (tid >> 3);
            const int col = (tid & 7) * 8;
            short8 d = *(const short8*)&src[((size_t)bh * S_DIM + t0 + row) * V_DIM + col];
            #pragma unroll
            for (int j = 0; j < 8; ++j) tl[pl][row][col + j] = (unsigned short)d[j];
        }
    }
    __syncthreads();
    #pragma unroll
    for (int pl = 0; pl < 2; ++pl) {
        unsigned short* dst = pl ? vit : vrt;
        #pragma unroll
        for (int p = 0; p < 2; ++p) {
            const int v = p * 32 + (tid >> 3);
            const int tc = (tid & 7) * 8;
            short8 d;
            #pragma unroll
            for (int j = 0; j < 8; ++j) d[j] = (short)tl[pl][tc + j][v];
            *(short8*)&dst[((size_t)bh * V_DIM + v) * S_DIM + t0 + tc] = d;
        }
    }
}

// ---------------- complex bf16 MFMA GEMM: C = A * B^T ----------------
// BK=64: two 32-K sub-tiles staged per barrier pair (halves barrier-drain count).
// NOTE: no min-waves launch bound — 2 waves/SIMD at ~190 VGPR; forcing 3 spills
// the 128-VGPR accumulator set to scratch (measured r4: WRITE_SIZE 82->959 MB).
// MODE 0: Mr=4096 (s,b), Nc=5120 (q|k|v) -> bf16 planes qr/qi/kr/ki/vr/vi
// MODE 2: Mr=4096, Nc=1024, split-K x2 (blockIdx.z); atomicAdd into zeroed out,
//         residual x added by the z==0 half.
template<int MODE>
__global__ __launch_bounds__(256) void cgemm(
    const unsigned short* __restrict__ Are, const unsigned short* __restrict__ Aim,
    const unsigned short* __restrict__ Bre, const unsigned short* __restrict__ Bim,
    unsigned short* __restrict__ qrp, unsigned short* __restrict__ qip,
    unsigned short* __restrict__ krp, unsigned short* __restrict__ kip,
    unsigned short* __restrict__ vrp, unsigned short* __restrict__ vip,
    const float* __restrict__ xre, const float* __restrict__ xim,
    float* __restrict__ out)
{
    // 64 KB: two 32 KB halves, each Are|Aim|Bre|Bim [128][32] tiles
    __shared__ unsigned short lds[32768];
    const int tid  = threadIdx.x;
    const int wave = tid >> 6;
    const int lane = tid & 63;
    const int r0 = blockIdx.x * 128;
    const int j0 = blockIdx.y * 128;
    const int wm = (wave >> 1) * 64;
    const int wn = (wave & 1) * 64;

    f32x4 accre[4][4], accim[4][4];
    #pragma unroll
    for (int i = 0; i < 4; ++i)
        #pragma unroll
        for (int j = 0; j < 4; ++j) {
            accre[i][j] = (f32x4){0.f, 0.f, 0.f, 0.f};
            accim[i][j] = (f32x4){0.f, 0.f, 0.f, 0.f};
        }

    const int srow = lane >> 2;          // staging: 4 lanes per 64B row
    const int scol = (lane & 3) * 8;
    const int lrow = lane & 15;          // frag: m/n index
    const int lk   = (lane >> 4) * 8;    // frag: k offset

    const int kbeg = (MODE == 2) ? (int)blockIdx.z * (E_DIM / 2) : 0;
    const int kend = (MODE == 2) ? kbeg + (E_DIM / 2) : E_DIM;

    for (int k0 = kbeg; k0 < kend; k0 += 64) {
        __syncthreads();
        #pragma unroll
        for (int kk = 0; kk < 2; ++kk) {
            #pragma unroll
            for (int c = 0; c < 2; ++c) {
                const int ag = (r0 + c * 64 + wave * 16 + srow) * E_DIM + k0 + kk * 32 + scol;
                const int bg = (j0 + c * 64 + wave * 16 + srow) * E_DIM + k0 + kk * 32 + scol;
                const int lb = kk * 16384 + wave * 512 + c * 2048;
                async16(Are + ag, &lds[lb]);
                async16(Aim + ag, &lds[4096 + lb]);
                async16(Bre + bg, &lds[8192 + lb]);
                async16(Bim + bg, &lds[12288 + lb]);
            }
        }
        __syncthreads();

        #pragma unroll
        for (int kk = 0; kk < 2; ++kk) {
            const int hb = kk * 16384;
            short8 ar[4], ai[4];
            #pragma unroll
            for (int im = 0; im < 4; ++im) {
                const int row = wm + im * 16 + lrow;
                ar[im] = *(const short8*)&lds[hb + row * 32 + lk];
                ai[im] = *(const short8*)&lds[hb + 4096 + row * 32 + lk];
            }
            #pragma unroll
            for (int jn = 0; jn < 4; ++jn) {
                const int row = wn + jn * 16 + lrow;
                const short8 br = *(const short8*)&lds[hb + 8192 + row * 32 + lk];
                const short8 bi = *(const short8*)&lds[hb + 12288 + row * 32 + lk];
                int4v t = *(int4v*)&bi;
                t = t ^ (int)0x80008000;       // bin = -bi (sign-bit flip, transient)
                const short8 bin = *(short8*)&t;
                #pragma unroll
                for (int im = 0; im < 4; ++im) {
                    accre[im][jn] = __builtin_amdgcn_mfma_f32_16x16x32_bf16(ar[im], br,  accre[im][jn], 0, 0, 0);
                    accre[im][jn] = __builtin_amdgcn_mfma_f32_16x16x32_bf16(ai[im], bin, accre[im][jn], 0, 0, 0);
                    accim[im][jn] = __builtin_amdgcn_mfma_f32_16x16x32_bf16(ar[im], bi,  accim[im][jn], 0, 0, 0);
                    accim[im][jn] = __builtin_amdgcn_mfma_f32_16x16x32_bf16(ai[im], br,  accim[im][jn], 0, 0, 0);
                }
            }
        }
    }

    // epilogue: D row = (lane>>4)*4+reg, col = lane&15  [measured m89/m91]
    #pragma unroll
    for (int im = 0; im < 4; ++im) {
        #pragma unroll
        for (int reg = 0; reg < 4; ++reg) {
            const int r = r0 + wm + im * 16 + (lane >> 4) * 4 + reg;
            #pragma unroll
            for (int jn = 0; jn < 4; ++jn) {
                const int j = j0 + wn + jn * 16 + (lane & 15);
                const float vr = accre[im][jn][reg];
                const float vi = accim[im][jn][reg];
                if (MODE == 0) {
                    const int s = r >> 2, b = r & 3;   // r = s*B + b
                    if (j < 2048) {
                        const int h = j >> 7, m = j & 127;
                        const size_t off = ((size_t)(b * H_DIM + h) * S_DIM + s) * M_DIM + m;
                        qrp[off] = f2bf(vr); qip[off] = f2bf(vi);
                    } else if (j < 4096) {
                        const int jl = j - 2048, h = jl >> 7, m = jl & 127;
                        const size_t off = ((size_t)(b * H_DIM + h) * S_DIM + s) * M_DIM + m;
                        krp[off] = f2bf(vr); kip[off] = f2bf(vi);
                    } else {
                        const int jl = j - 4096, h = jl >> 6, vv = jl & 63;
                        const size_t off = ((size_t)(b * H_DIM + h) * S_DIM + s) * V_DIM + vv;
                        vrp[off] = f2bf(vr); vip[off] = f2bf(vi);
                    }
                } else {
                    const int idx = r * E_DIM + j;
                    float addr_ = vr, addi_ = vi;
                    if (blockIdx.z == 0) { addr_ += xre[idx]; addi_ += xim[idx]; }
                    unsafeAtomicAdd(&out[idx], addr_);
                    unsafeAtomicAdd(&out[S_DIM * B_DIM * E_DIM + idx], addi_);
                }
            }
        }
    }
}

// ---------------- K2: MFMA flash attention ----------------
// block = one (b,h) x 64 q rows; 4 waves x 16 rows; K-tile 64.
// Staging is software-pipelined: next K/V tile is loaded into registers while
// the current tile is being consumed from LDS.
__global__ __launch_bounds__(256, 2) void attn_mfma(
    const unsigned short* __restrict__ qr, const unsigned short* __restrict__ qi,
    const unsigned short* __restrict__ kr, const unsigned short* __restrict__ ki,
    const unsigned short* __restrict__ vrt, const unsigned short* __restrict__ vit,
    unsigned short* __restrict__ updre, unsigned short* __restrict__ updim)
{
    __shared__ __align__(16) unsigned short Ks[2][64][136];  // K tile [plane][t][m] (Q staged here first)
    __shared__ __align__(16) unsigned short Vs[2][64][72];   // V^T tile [plane][v][t]
    __shared__ __align__(16) unsigned short Ps[4][16][72];   // per-wave P [q][t]

    const int tid  = threadIdx.x;
    const int wave = tid >> 6;
    const int lane = tid & 63;
    const int qt = (int)gridDim.x - 1 - blockIdx.x;  // long blocks launch first
    const int bh = blockIdx.y;
    const int q0 = qt * 64;
    const size_t base_qk = (size_t)bh * S_DIM * M_DIM;
    const size_t base_v  = (size_t)bh * V_DIM * S_DIM;

    const int fr = lane & 15;        // frag m/n index
    const int fg = lane >> 4;        // 0..3
    const int fk = fg * 8;           // frag k offset (bf16)

    // staging coords
    const int krow = tid >> 4, kcol = (tid & 15) * 8;   // K: 16 rows/pass
    const int vrow = tid >> 3, vcol = (tid & 7) * 8;    // V: 32 rows/pass

    // ---- stage Q tile into Ks, extract per-wave A-frags to registers ----
    #pragma unroll
    for (int pl = 0; pl < 2; ++pl) {
        const unsigned short* src = pl ? qi : qr;
        #pragma unroll
        for (int p = 0; p < 4; ++p)
            *(short8*)&Ks[pl][p * 16 + krow][kcol] =
                *(const short8*)&src[base_qk + (size_t)(q0 + p * 16 + krow) * M_DIM + kcol];
    }
    __syncthreads();
    short8 Aqr[4], Aqi[4], Aqin[4];
    {
        const int qrow = wave * 16 + fr;
        #pragma unroll
        for (int ks = 0; ks < 4; ++ks) {
            Aqr[ks] = *(const short8*)&Ks[0][qrow][ks * 32 + fk];
            Aqi[ks] = *(const short8*)&Ks[1][qrow][ks * 32 + fk];
            int4v t = *(int4v*)&Aqi[ks];
            t = t ^ (int)0x80008000;
            Aqin[ks] = *(short8*)&t;
        }
    }

    f32x4 Ore[4], Oim[4];
    #pragma unroll
    for (int vt = 0; vt < 4; ++vt) {
        Ore[vt] = (f32x4){0.f, 0.f, 0.f, 0.f};
        Oim[vt] = (f32x4){0.f, 0.f, 0.f, 0.f};
    }
    float mrun[4] = {-INFINITY, -INFINITY, -INFINITY, -INFINITY};
    float lrun[4] = {0.f, 0.f, 0.f, 0.f};

    const float scale = 0.088388347648318447f;  // 1/sqrt(128)
    const int qbase = q0 + wave * 16 + fg * 4;  // + reg = global q row

    // ---- prefetch tile t0=0 into registers ----
    short8 pk[2][4], pv[2][2];
    #pragma unroll
    for (int pl = 0; pl < 2; ++pl) {
        const unsigned short* src = pl ? ki : kr;
        #pragma unroll
        for (int p = 0; p < 4; ++p)
            pk[pl][p] = *(const short8*)&src[base_qk + (size_t)(p * 16 + krow) * M_DIM + kcol];
    }
    #pragma unroll
    for (int pl = 0; pl < 2; ++pl) {
        const unsigned short* src = pl ? vit : vrt;
        #pragma unroll
        for (int p = 0; p < 2; ++p)
            pv[pl][p] = *(const short8*)&src[base_v + (size_t)(p * 32 + vrow) * S_DIM + vcol];
    }

    for (int t0 = 0; t0 <= q0; t0 += 64) {
        __syncthreads();   // prior readers of Ks/Vs done (iter0: Q frags extracted)
        // ---- commit prefetched K/V tile to LDS ----
        #pragma unroll
        for (int pl = 0; pl < 2; ++pl) {
            #pragma unroll
            for (int p = 0; p < 4; ++p)
                *(short8*)&Ks[pl][p * 16 + krow][kcol] = pk[pl][p];
            #pragma unroll
            for (int p = 0; p < 2; ++p)
                *(short8*)&Vs[pl][p * 32 + vrow][vcol] = pv[pl][p];
        }
        __syncthreads();

        // ---- issue next tile's global loads (consumed next iteration) ----
        if (t0 + 64 <= q0) {
            const int tn = t0 + 64;
            #pragma unroll
            for (int pl = 0; pl < 2; ++pl) {
                const unsigned short* src = pl ? ki : kr;
                #pragma unroll
                for (int p = 0; p < 4; ++p)
                    pk[pl][p] = *(const short8*)&src[base_qk + (size_t)(tn + p * 16 + krow) * M_DIM + kcol];
            }
            #pragma unroll
            for (int pl = 0; pl < 2; ++pl) {
                const unsigned short* src = pl ? vit : vrt;
                #pragma unroll
                for (int p = 0; p < 2; ++p)
                    pv[pl][p] = *(const short8*)&src[base_v + (size_t)(p * 32 + vrow) * S_DIM + tn + vcol];
            }
        }

        // ---- QK^T (complex) into S fragments ----
        f32x4 Sre[4], Sim[4];
        #pragma unroll
        for (int tt = 0; tt < 4; ++tt) {
            Sre[tt] = (f32x4){0.f, 0.f, 0.f, 0.f};
            Sim[tt] = (f32x4){0.f, 0.f, 0.f, 0.f};
            const int trow = tt * 16 + fr;
            #pragma unroll
            for (int ks = 0; ks < 4; ++ks) {
                const short8 Bkr = *(const short8*)&Ks[0][trow][ks * 32 + fk];
                const short8 Bki = *(const short8*)&Ks[1][trow][ks * 32 + fk];
                Sre[tt] = __builtin_amdgcn_mfma_f32_16x16x32_bf16(Aqr[ks],  Bkr, Sre[tt], 0, 0, 0);
                Sre[tt] = __builtin_amdgcn_mfma_f32_16x16x32_bf16(Aqin[ks], Bki, Sre[tt], 0, 0, 0);
                Sim[tt] = __builtin_amdgcn_mfma_f32_16x16x32_bf16(Aqr[ks],  Bki, Sim[tt], 0, 0, 0);
                Sim[tt] = __builtin_amdgcn_mfma_f32_16x16x32_bf16(Aqi[ks],  Bkr, Sim[tt], 0, 0, 0);
            }
        }

        // ---- amplitude + causal mask + online softmax (register state) ----
        float amp[4][4];
        #pragma unroll
        for (int tt = 0; tt < 4; ++tt) {
            const int tg = t0 + tt * 16 + fr;
            #pragma unroll
            for (int r = 0; r < 4; ++r) {
                const float re = Sre[tt][r], im = Sim[tt][r];
                const float a = sqrtf(re * re + im * im) * scale;
                amp[tt][r] = (tg > qbase + r) ? -INFINITY : a;
            }
        }
        float al[4];
        #pragma unroll
        for (int r = 0; r < 4; ++r) {
            float rm = fmaxf(fmaxf(amp[0][r], amp[1][r]), fmaxf(amp[2][r], amp[3][r]));
            rm = fmaxf(rm, __shfl_xor(rm, 1));
            rm = fmaxf(rm, __shfl_xor(rm, 2));
            rm = fmaxf(rm, __shfl_xor(rm, 4));
            rm = fmaxf(rm, __shfl_xor(rm, 8));
            const float nm = fmaxf(mrun[r], rm);
            al[r] = __expf(mrun[r] - nm);
            mrun[r] = nm;
            float psum = 0.f;
            #pragma unroll
            for (int tt = 0; tt < 4; ++tt) {
                const float p = __expf(amp[tt][r] - nm);
                psum += p;
                Ps[wave][fg * 4 + r][tt * 16 + fr] = f2bf(p);
            }
            psum += __shfl_xor(psum, 1);
            psum += __shfl_xor(psum, 2);
            psum += __shfl_xor(psum, 4);
            psum += __shfl_xor(psum, 8);
            lrun[r] = lrun[r] * al[r] + psum;
        }
        #pragma unroll
        for (int vt = 0; vt < 4; ++vt)
            #pragma unroll
            for (int r = 0; r < 4; ++r) { Ore[vt][r] *= al[r]; Oim[vt][r] *= al[r]; }

        // ---- PV: P (A-layout via per-wave LDS) x V^T fragments ----
        short8 Pa0 = *(const short8*)&Ps[wave][fr][fk];
        short8 Pa1 = *(const short8*)&Ps[wave][fr][32 + fk];
        #pragma unroll
        for (int vt = 0; vt < 4; ++vt) {
            const int vr2 = vt * 16 + fr;
            short8 B0r = *(const short8*)&Vs[0][vr2][fk];
            short8 B1r = *(const short8*)&Vs[0][vr2][32 + fk];
            short8 B0i = *(const short8*)&Vs[1][vr2][fk];
            short8 B1i = *(const short8*)&Vs[1][vr2][32 + fk];
            Ore[vt] = __builtin_amdgcn_mfma_f32_16x16x32_bf16(Pa0, B0r, Ore[vt], 0, 0, 0);
            Ore[vt] = __builtin_amdgcn_mfma_f32_16x16x32_bf16(Pa1, B1r, Ore[vt], 0, 0, 0);
            Oim[vt] = __builtin_amdgcn_mfma_f32_16x16x32_bf16(Pa0, B0i, Oim[vt], 0, 0, 0);
            Oim[vt] = __builtin_amdgcn_mfma_f32_16x16x32_bf16(Pa1, B1i, Oim[vt], 0, 0, 0);
        }
    }

    // ---- epilogue ----
    const int b = bh >> 4, h = bh & 15;
    float inv[4];
    #pragma unroll
    for (int r = 0; r < 4; ++r) inv[r] = 1.0f / lrun[r];
    #pragma unroll
    for (int vt = 0; vt < 4; ++vt) {
        #pragma unroll
        for (int r = 0; r < 4; ++r) {
            const int s = qbase + r;
            const size_t off = ((size_t)(s * B_DIM + b)) * E_DIM + h * V_DIM + vt * 16 + fr;
            updre[off] = f2bf(Ore[vt][r] * inv[r]);
            updim[off] = f2bf(Oim[vt][r] * inv[r]);
        }
    }
}

extern "C" void kernel_launch(void* const* d_in, const int* in_sizes, int n_in,
                              void* d_out, int out_size, void* d_ws, size_t ws_size,
                              hipStream_t stream) {
    const float* xre  = (const float*)d_in[0];
    const float* xim  = (const float*)d_in[1];
    const float* wqre = (const float*)d_in[2];
    const float* wqim = (const float*)d_in[3];
    const float* wkre = (const float*)d_in[4];
    const float* wkim = (const float*)d_in[5];
    const float* wvre = (const float*)d_in[6];
    const float* wvim = (const float*)d_in[7];
    const float* wore = (const float*)d_in[8];
    const float* woim = (const float*)d_in[9];
    float* out = (float*)d_out;

    // workspace layout (~160 MB)
    char* p = (char*)d_ws;
    const size_t QK = (size_t)B_DIM * H_DIM * S_DIM * M_DIM;   // 8.39M
    const size_t VS = (size_t)B_DIM * H_DIM * S_DIM * V_DIM;   // 4.19M
    const size_t SBE = (size_t)S_DIM * B_DIM * E_DIM;          // 4.19M
    unsigned short* qrw = (unsigned short*)p;  p += QK * 2;
    unsigned short* qiw = (unsigned short*)p;  p += QK * 2;
    unsigned short* krw = (unsigned short*)p;  p += QK * 2;
    unsigned short* kiw = (unsigned short*)p;  p += QK * 2;
    unsigned short* vrw = (unsigned short*)p;  p += VS * 2;
    unsigned short* viw = (unsigned short*)p;  p += VS * 2;
    unsigned short* vrt = (unsigned short*)p;  p += VS * 2;
    unsigned short* vit = (unsigned short*)p;  p += VS * 2;
    unsigned short* updre = (unsigned short*)p; p += SBE * 2;
    unsigned short* updim = (unsigned short*)p; p += SBE * 2;
    unsigned short* xbre  = (unsigned short*)p; p += SBE * 2;
    unsigned short* xbim  = (unsigned short*)p; p += SBE * 2;
    unsigned short* wbre  = (unsigned short*)p; p += (size_t)5120 * E_DIM * 2;
    unsigned short* wbim  = (unsigned short*)p; p += (size_t)5120 * E_DIM * 2;
    unsigned short* wtre  = (unsigned short*)p; p += (size_t)E_DIM * E_DIM * 2;
    unsigned short* wtim  = (unsigned short*)p; p += (size_t)E_DIM * E_DIM * 2;

    // bf16 conversion passes
    convert_pair<<<4096, 256, 0, stream>>>(xre, xim, xbre, xbim, 1048576);
    convert_pair<<<2048, 256, 0, stream>>>(wqre, wqim, wbre, wbim, 524288);
    convert_pair<<<2048, 256, 0, stream>>>(wkre, wkim, wbre + 2048*1024, wbim + 2048*1024, 524288);
    convert_pair<<<1024, 256, 0, stream>>>(wvre, wvim, wbre + 4096*1024, wbim + 4096*1024, 262144);
    transpose_wo<<<dim3(32, 32), 256, 0, stream>>>(wore, woim, wtre, wtim);

    // QKV projection (bf16 MFMA) -> separated planes
    cgemm<0><<<dim3(32, 40), 256, 0, stream>>>(xbre, xbim, wbre, wbim,
                                               qrw, qiw, krw, kiw, vrw, viw,
                                               nullptr, nullptr, nullptr);
    // V -> V^T planes
    vtrans<<<dim3(16, 64), 256, 0, stream>>>(vrw, viw, vrt, vit);
    // MFMA flash attention
    attn_mfma<<<dim3(16, 64), 256, 0, stream>>>(qrw, qiw, krw, kiw, vrt, vit, updre, updim);
    // output projection + residual: zero-init out, then split-K x2 atomic accumulate
    hipMemsetAsync(out, 0, (size_t)2 * SBE * sizeof(float), stream);
    cgemm<2><<<dim3(32, 8, 2), 256, 0, stream>>>(updre, updim, wtre, wtim,
                                                 nullptr, nullptr, nullptr, nullptr, nullptr, nullptr,
                                                 xre, xim, out);
}

// Round 6
// 507.466 us; speedup vs baseline: 1.5208x; 1.2791x over previous
//
#include <hip/hip_runtime.h>
#include <math.h>

#define S_DIM 1024
#define B_DIM 4
#define E_DIM 1024
#define H_DIM 16
#define M_DIM 128
#define V_DIM 64

typedef __attribute__((ext_vector_type(8))) short short8;
typedef __attribute__((ext_vector_type(4))) float f32x4;
typedef __attribute__((ext_vector_type(4))) int int4v;

__device__ __forceinline__ unsigned short f2bf(float f) {
    union { float f; unsigned u; } v; v.f = f;
    unsigned r = v.u + 0x7FFFu + ((v.u >> 16) & 1u);   // round-to-nearest-even
    return (unsigned short)(r >> 16);
}

__device__ __forceinline__ void async16(const unsigned short* g, unsigned short* l) {
    __builtin_amdgcn_global_load_lds(
        (const __attribute__((address_space(1))) void*)g,
        (__attribute__((address_space(3))) void*)l,
        16, 0, 0);
}

// ---------------- convert: fp32 (re,im) -> bf16 arrays ----------------
__global__ __launch_bounds__(256) void convert_pair(
    const float* __restrict__ re, const float* __restrict__ im,
    unsigned short* __restrict__ dre, unsigned short* __restrict__ dim_, int n4)
{
    int i = blockIdx.x * 256 + threadIdx.x;
    if (i >= n4) return;
    float4 r = ((const float4*)re)[i];
    float4 m = ((const float4*)im)[i];
    ushort4 ro, mo;
    ro.x = f2bf(r.x); ro.y = f2bf(r.y); ro.z = f2bf(r.z); ro.w = f2bf(r.w);
    mo.x = f2bf(m.x); mo.y = f2bf(m.y); mo.z = f2bf(m.z); mo.w = f2bf(m.w);
    ((ushort4*)dre)[i] = ro;
    ((ushort4*)dim_)[i] = mo;
}

// wo (e,f) -> woT (f,e) bf16
__global__ __launch_bounds__(256) void transpose_wo(
    const float* __restrict__ wore, const float* __restrict__ woim,
    unsigned short* __restrict__ wtre, unsigned short* __restrict__ wtim)
{
    __shared__ float tr[32][33], ti[32][33];
    const int bx = blockIdx.x * 32;   // e range
    const int by = blockIdx.y * 32;   // f range
    const int tx = threadIdx.x & 31, ty = threadIdx.x >> 5;
    for (int i = ty; i < 32; i += 8) {
        tr[i][tx] = wore[(bx + i) * E_DIM + by + tx];
        ti[i][tx] = woim[(bx + i) * E_DIM + by + tx];
    }
    __syncthreads();
    for (int i = ty; i < 32; i += 8) {
        wtre[(by + i) * E_DIM + bx + tx] = f2bf(tr[tx][i]);
        wtim[(by + i) * E_DIM + bx + tx] = f2bf(ti[tx][i]);
    }
}

// v planes [bh][t][64] -> v^T planes [bh][v][1024]
__global__ __launch_bounds__(256) void vtrans(
    const unsigned short* __restrict__ vrp, const unsigned short* __restrict__ vip,
    unsigned short* __restrict__ vrt, unsigned short* __restrict__ vit)
{
    __shared__ unsigned short tl[2][64][66];
    const int tid = threadIdx.x;
    const int t0 = blockIdx.x * 64;
    const int bh = blockIdx.y;
    #pragma unroll
    for (int pl = 0; pl < 2; ++pl) {
        const unsigned short* src = pl ? vip : vrp;
        #pragma unroll
        for (int p = 0; p < 2; ++p) {
            const int row = p * 32 + (tid >> 3);
            const int col = (tid & 7) * 8;
            short8 d = *(const short8*)&src[((size_t)bh * S_DIM + t0 + row) * V_DIM + col];
            #pragma unroll
            for (int j = 0; j < 8; ++j) tl[pl][row][col + j] = (unsigned short)d[j];
        }
    }
    __syncthreads();
    #pragma unroll
    for (int pl = 0; pl < 2; ++pl) {
        unsigned short* dst = pl ? vit : vrt;
        #pragma unroll
        for (int p = 0; p < 2; ++p) {
            const int v = p * 32 + (tid >> 3);
            const int tc = (tid & 7) * 8;
            short8 d;
            #pragma unroll
            for (int j = 0; j < 8; ++j) d[j] = (short)tl[pl][tc + j][v];
            *(short8*)&dst[((size_t)bh * V_DIM + v) * S_DIM + t0 + tc] = d;
        }
    }
}

// ---------------- complex bf16 MFMA GEMM: C = A * B^T ----------------
// Block tile 128x64, 2x2 waves of 64x32 -> acc is 64 VGPR (vs 128 for 64x64),
// natural usage ~140 VGPR so (256,3) is safe (r4's spill: kernel NEEDED 190
// under a 170 cap; here it doesn't). LDS 48 KB -> 3 blocks/CU = 3 waves/SIMD.
// BK=64: two 32-K sub-tiles staged per barrier pair.
// MODE 0: Mr=4096 (s,b), Nc=5120 (q|k|v) -> bf16 planes qr/qi/kr/ki/vr/vi
// MODE 1: Mr=4096, Nc=1024 -> out = acc + x (fp32, stacked re/im), plain stores
template<int MODE>
__global__ __launch_bounds__(256, 3) void cgemm(
    const unsigned short* __restrict__ Are, const unsigned short* __restrict__ Aim,
    const unsigned short* __restrict__ Bre, const unsigned short* __restrict__ Bim,
    unsigned short* __restrict__ qrp, unsigned short* __restrict__ qip,
    unsigned short* __restrict__ krp, unsigned short* __restrict__ kip,
    unsigned short* __restrict__ vrp, unsigned short* __restrict__ vip,
    const float* __restrict__ xre, const float* __restrict__ xim,
    float* __restrict__ out)
{
    // 48 KB: 2 kk-halves x (Ar[128][32] | Ai[128][32] | Br[64][32] | Bi[64][32])
    __shared__ unsigned short lds[24576];
    const int tid  = threadIdx.x;
    const int wave = tid >> 6;
    const int lane = tid & 63;
    const int r0 = blockIdx.x * 128;
    const int j0 = blockIdx.y * 64;
    const int wm = (wave >> 1) * 64;   // m half
    const int wn = (wave & 1) * 32;    // n half

    f32x4 accre[4][2], accim[4][2];
    #pragma unroll
    for (int i = 0; i < 4; ++i)
        #pragma unroll
        for (int j = 0; j < 2; ++j) {
            accre[i][j] = (f32x4){0.f, 0.f, 0.f, 0.f};
            accim[i][j] = (f32x4){0.f, 0.f, 0.f, 0.f};
        }

    const int srow = lane >> 2;          // staging: 4 lanes per 64B row
    const int scol = (lane & 3) * 8;
    const int fr = lane & 15;            // frag: m/n index
    const int fk = (lane >> 4) * 8;      // frag: k offset

    for (int k0 = 0; k0 < E_DIM; k0 += 64) {
        __syncthreads();
        #pragma unroll
        for (int kk = 0; kk < 2; ++kk) {
            const int kb = kk * 12288;
            const int kg = k0 + kk * 32;
            // A planes: this wave stages rows [wave*32, wave*32+32)
            #pragma unroll
            for (int c = 0; c < 2; ++c) {
                const int row0 = wave * 32 + c * 16;
                const int g = (r0 + row0 + srow) * E_DIM + kg + scol;
                async16(Are + g, &lds[kb + row0 * 32]);
                async16(Aim + g, &lds[kb + 4096 + row0 * 32]);
            }
            // B planes: this wave stages rows [wave*16, wave*16+16)
            {
                const int row0 = wave * 16;
                const int g = (j0 + row0 + srow) * E_DIM + kg + scol;
                async16(Bre + g, &lds[kb + 8192 + row0 * 32]);
                async16(Bim + g, &lds[kb + 10240 + row0 * 32]);
            }
        }
        __syncthreads();

        #pragma unroll
        for (int kk = 0; kk < 2; ++kk) {
            const int kb = kk * 12288;
            short8 ar[4], ai[4];
            #pragma unroll
            for (int im = 0; im < 4; ++im) {
                const int row = wm + im * 16 + fr;
                ar[im] = *(const short8*)&lds[kb + row * 32 + fk];
                ai[im] = *(const short8*)&lds[kb + 4096 + row * 32 + fk];
            }
            #pragma unroll
            for (int jn = 0; jn < 2; ++jn) {
                const int row = wn + jn * 16 + fr;
                const short8 br = *(const short8*)&lds[kb + 8192 + row * 32 + fk];
                const short8 bi = *(const short8*)&lds[kb + 10240 + row * 32 + fk];
                int4v t = *(int4v*)&bi;
                t = t ^ (int)0x80008000;       // bin = -bi (transient)
                const short8 bin = *(short8*)&t;
                #pragma unroll
                for (int im = 0; im < 4; ++im) {
                    accre[im][jn] = __builtin_amdgcn_mfma_f32_16x16x32_bf16(ar[im], br,  accre[im][jn], 0, 0, 0);
                    accre[im][jn] = __builtin_amdgcn_mfma_f32_16x16x32_bf16(ai[im], bin, accre[im][jn], 0, 0, 0);
                    accim[im][jn] = __builtin_amdgcn_mfma_f32_16x16x32_bf16(ar[im], bi,  accim[im][jn], 0, 0, 0);
                    accim[im][jn] = __builtin_amdgcn_mfma_f32_16x16x32_bf16(ai[im], br,  accim[im][jn], 0, 0, 0);
                }
            }
        }
    }

    // epilogue: D row = (lane>>4)*4+reg, col = lane&15  [measured m89/m91]
    #pragma unroll
    for (int im = 0; im < 4; ++im) {
        #pragma unroll
        for (int reg = 0; reg < 4; ++reg) {
            const int r = r0 + wm + im * 16 + (lane >> 4) * 4 + reg;
            #pragma unroll
            for (int jn = 0; jn < 2; ++jn) {
                const int j = j0 + wn + jn * 16 + fr;
                const float vr = accre[im][jn][reg];
                const float vi = accim[im][jn][reg];
                if (MODE == 0) {
                    const int s = r >> 2, b = r & 3;   // r = s*B + b
                    if (j < 2048) {
                        const int h = j >> 7, m = j & 127;
                        const size_t off = ((size_t)(b * H_DIM + h) * S_DIM + s) * M_DIM + m;
                        qrp[off] = f2bf(vr); qip[off] = f2bf(vi);
                    } else if (j < 4096) {
                        const int jl = j - 2048, h = jl >> 7, m = jl & 127;
                        const size_t off = ((size_t)(b * H_DIM + h) * S_DIM + s) * M_DIM + m;
                        krp[off] = f2bf(vr); kip[off] = f2bf(vi);
                    } else {
                        const int jl = j - 4096, h = jl >> 6, vv = jl & 63;
                        const size_t off = ((size_t)(b * H_DIM + h) * S_DIM + s) * V_DIM + vv;
                        vrp[off] = f2bf(vr); vip[off] = f2bf(vi);
                    }
                } else {
                    const int idx = r * E_DIM + j;
                    out[idx] = vr + xre[idx];
                    out[S_DIM * B_DIM * E_DIM + idx] = vi + xim[idx];
                }
            }
        }
    }
}

// ---------------- K2: MFMA flash attention ----------------
// block = one (b,h) x 64 q rows; 4 waves x 16 rows; K-tile 64.
// Software-pipelined staging; B-imag negated transiently (no Aqin residency).
__global__ __launch_bounds__(256, 2) void attn_mfma(
    const unsigned short* __restrict__ qr, const unsigned short* __restrict__ qi,
    const unsigned short* __restrict__ kr, const unsigned short* __restrict__ ki,
    const unsigned short* __restrict__ vrt, const unsigned short* __restrict__ vit,
    unsigned short* __restrict__ updre, unsigned short* __restrict__ updim)
{
    __shared__ __align__(16) unsigned short Ks[2][64][136];  // K tile [plane][t][m] (Q staged here first)
    __shared__ __align__(16) unsigned short Vs[2][64][72];   // V^T tile [plane][v][t]
    __shared__ __align__(16) unsigned short Ps[4][16][72];   // per-wave P [q][t]

    const int tid  = threadIdx.x;
    const int wave = tid >> 6;
    const int lane = tid & 63;
    const int qt = (int)gridDim.x - 1 - blockIdx.x;  // long blocks launch first
    const int bh = blockIdx.y;
    const int q0 = qt * 64;
    const size_t base_qk = (size_t)bh * S_DIM * M_DIM;
    const size_t base_v  = (size_t)bh * V_DIM * S_DIM;

    const int fr = lane & 15;        // frag m/n index
    const int fg = lane >> 4;        // 0..3
    const int fk = fg * 8;           // frag k offset (bf16)

    // staging coords
    const int krow = tid >> 4, kcol = (tid & 15) * 8;   // K: 16 rows/pass
    const int vrow = tid >> 3, vcol = (tid & 7) * 8;    // V: 32 rows/pass

    // ---- stage Q tile into Ks, extract per-wave A-frags to registers ----
    #pragma unroll
    for (int pl = 0; pl < 2; ++pl) {
        const unsigned short* src = pl ? qi : qr;
        #pragma unroll
        for (int p = 0; p < 4; ++p)
            *(short8*)&Ks[pl][p * 16 + krow][kcol] =
                *(const short8*)&src[base_qk + (size_t)(q0 + p * 16 + krow) * M_DIM + kcol];
    }
    __syncthreads();
    short8 Aqr[4], Aqi[4];
    {
        const int qrow = wave * 16 + fr;
        #pragma unroll
        for (int ks = 0; ks < 4; ++ks) {
            Aqr[ks] = *(const short8*)&Ks[0][qrow][ks * 32 + fk];
            Aqi[ks] = *(const short8*)&Ks[1][qrow][ks * 32 + fk];
        }
    }

    f32x4 Ore[4], Oim[4];
    #pragma unroll
    for (int vt = 0; vt < 4; ++vt) {
        Ore[vt] = (f32x4){0.f, 0.f, 0.f, 0.f};
        Oim[vt] = (f32x4){0.f, 0.f, 0.f, 0.f};
    }
    float mrun[4] = {-INFINITY, -INFINITY, -INFINITY, -INFINITY};
    float lrun[4] = {0.f, 0.f, 0.f, 0.f};

    const float scale = 0.088388347648318447f;  // 1/sqrt(128)
    const int qbase = q0 + wave * 16 + fg * 4;  // + reg = global q row

    // ---- prefetch tile t0=0 into registers ----
    short8 pk[2][4], pv[2][2];
    #pragma unroll
    for (int pl = 0; pl < 2; ++pl) {
        const unsigned short* src = pl ? ki : kr;
        #pragma unroll
        for (int p = 0; p < 4; ++p)
            pk[pl][p] = *(const short8*)&src[base_qk + (size_t)(p * 16 + krow) * M_DIM + kcol];
    }
    #pragma unroll
    for (int pl = 0; pl < 2; ++pl) {
        const unsigned short* src = pl ? vit : vrt;
        #pragma unroll
        for (int p = 0; p < 2; ++p)
            pv[pl][p] = *(const short8*)&src[base_v + (size_t)(p * 32 + vrow) * S_DIM + vcol];
    }

    for (int t0 = 0; t0 <= q0; t0 += 64) {
        __syncthreads();   // prior readers of Ks/Vs done (iter0: Q frags extracted)
        // ---- commit prefetched K/V tile to LDS ----
        #pragma unroll
        for (int pl = 0; pl < 2; ++pl) {
            #pragma unroll
            for (int p = 0; p < 4; ++p)
                *(short8*)&Ks[pl][p * 16 + krow][kcol] = pk[pl][p];
            #pragma unroll
            for (int p = 0; p < 2; ++p)
                *(short8*)&Vs[pl][p * 32 + vrow][vcol] = pv[pl][p];
        }
        __syncthreads();

        // ---- issue next tile's global loads (consumed next iteration) ----
        if (t0 + 64 <= q0) {
            const int tn = t0 + 64;
            #pragma unroll
            for (int pl = 0; pl < 2; ++pl) {
                const unsigned short* src = pl ? ki : kr;
                #pragma unroll
                for (int p = 0; p < 4; ++p)
                    pk[pl][p] = *(const short8*)&src[base_qk + (size_t)(tn + p * 16 + krow) * M_DIM + kcol];
            }
            #pragma unroll
            for (int pl = 0; pl < 2; ++pl) {
                const unsigned short* src = pl ? vit : vrt;
                #pragma unroll
                for (int p = 0; p < 2; ++p)
                    pv[pl][p] = *(const short8*)&src[base_v + (size_t)(p * 32 + vrow) * S_DIM + tn + vcol];
            }
        }

        // ---- QK^T (complex) into S fragments ----
        f32x4 Sre[4], Sim[4];
        #pragma unroll
        for (int tt = 0; tt < 4; ++tt) {
            Sre[tt] = (f32x4){0.f, 0.f, 0.f, 0.f};
            Sim[tt] = (f32x4){0.f, 0.f, 0.f, 0.f};
            const int trow = tt * 16 + fr;
            #pragma unroll
            for (int ks = 0; ks < 4; ++ks) {
                const short8 Bkr = *(const short8*)&Ks[0][trow][ks * 32 + fk];
                const short8 Bki = *(const short8*)&Ks[1][trow][ks * 32 + fk];
                int4v t = *(int4v*)&Bki;
                t = t ^ (int)0x80008000;       // -Bki (transient)
                const short8 Bkin = *(short8*)&t;
                Sre[tt] = __builtin_amdgcn_mfma_f32_16x16x32_bf16(Aqr[ks], Bkr,  Sre[tt], 0, 0, 0);
                Sre[tt] = __builtin_amdgcn_mfma_f32_16x16x32_bf16(Aqi[ks], Bkin, Sre[tt], 0, 0, 0);
                Sim[tt] = __builtin_amdgcn_mfma_f32_16x16x32_bf16(Aqr[ks], Bki,  Sim[tt], 0, 0, 0);
                Sim[tt] = __builtin_amdgcn_mfma_f32_16x16x32_bf16(Aqi[ks], Bkr,  Sim[tt], 0, 0, 0);
            }
        }

        // ---- amplitude + causal mask + online softmax (register state) ----
        float amp[4][4];
        #pragma unroll
        for (int tt = 0; tt < 4; ++tt) {
            const int tg = t0 + tt * 16 + fr;
            #pragma unroll
            for (int r = 0; r < 4; ++r) {
                const float re = Sre[tt][r], im = Sim[tt][r];
                const float a = sqrtf(re * re + im * im) * scale;
                amp[tt][r] = (tg > qbase + r) ? -INFINITY : a;
            }
        }
        float al[4];
        #pragma unroll
        for (int r = 0; r < 4; ++r) {
            float rm = fmaxf(fmaxf(amp[0][r], amp[1][r]), fmaxf(amp[2][r], amp[3][r]));
            rm = fmaxf(rm, __shfl_xor(rm, 1));
            rm = fmaxf(rm, __shfl_xor(rm, 2));
            rm = fmaxf(rm, __shfl_xor(rm, 4));
            rm = fmaxf(rm, __shfl_xor(rm, 8));
            const float nm = fmaxf(mrun[r], rm);
            al[r] = __expf(mrun[r] - nm);
            mrun[r] = nm;
            float psum = 0.f;
            #pragma unroll
            for (int tt = 0; tt < 4; ++tt) {
                const float p = __expf(amp[tt][r] - nm);
                psum += p;
                Ps[wave][fg * 4 + r][tt * 16 + fr] = f2bf(p);
            }
            psum += __shfl_xor(psum, 1);
            psum += __shfl_xor(psum, 2);
            psum += __shfl_xor(psum, 4);
            psum += __shfl_xor(psum, 8);
            lrun[r] = lrun[r] * al[r] + psum;
        }
        #pragma unroll
        for (int vt = 0; vt < 4; ++vt)
            #pragma unroll
            for (int r = 0; r < 4; ++r) { Ore[vt][r] *= al[r]; Oim[vt][r] *= al[r]; }

        // ---- PV: P (A-layout via per-wave LDS) x V^T fragments ----
        short8 Pa0 = *(const short8*)&Ps[wave][fr][fk];
        short8 Pa1 = *(const short8*)&Ps[wave][fr][32 + fk];
        #pragma unroll
        for (int vt = 0; vt < 4; ++vt) {
            const int vr2 = vt * 16 + fr;
            short8 B0r = *(const short8*)&Vs[0][vr2][fk];
            short8 B1r = *(const short8*)&Vs[0][vr2][32 + fk];
            short8 B0i = *(const short8*)&Vs[1][vr2][fk];
            short8 B1i = *(const short8*)&Vs[1][vr2][32 + fk];
            Ore[vt] = __builtin_amdgcn_mfma_f32_16x16x32_bf16(Pa0, B0r, Ore[vt], 0, 0, 0);
            Ore[vt] = __builtin_amdgcn_mfma_f32_16x16x32_bf16(Pa1, B1r, Ore[vt], 0, 0, 0);
            Oim[vt] = __builtin_amdgcn_mfma_f32_16x16x32_bf16(Pa0, B0i, Oim[vt], 0, 0, 0);
            Oim[vt] = __builtin_amdgcn_mfma_f32_16x16x32_bf16(Pa1, B1i, Oim[vt], 0, 0, 0);
        }
    }

    // ---- epilogue ----
    const int b = bh >> 4, h = bh & 15;
    float inv[4];
    #pragma unroll
    for (int r = 0; r < 4; ++r) inv[r] = 1.0f / lrun[r];
    #pragma unroll
    for (int vt = 0; vt < 4; ++vt) {
        #pragma unroll
        for (int r = 0; r < 4; ++r) {
            const int s = qbase + r;
            const size_t off = ((size_t)(s * B_DIM + b)) * E_DIM + h * V_DIM + vt * 16 + fr;
            updre[off] = f2bf(Ore[vt][r] * inv[r]);
            updim[off] = f2bf(Oim[vt][r] * inv[r]);
        }
    }
}

extern "C" void kernel_launch(void* const* d_in, const int* in_sizes, int n_in,
                              void* d_out, int out_size, void* d_ws, size_t ws_size,
                              hipStream_t stream) {
    const float* xre  = (const float*)d_in[0];
    const float* xim  = (const float*)d_in[1];
    const float* wqre = (const float*)d_in[2];
    const float* wqim = (const float*)d_in[3];
    const float* wkre = (const float*)d_in[4];
    const float* wkim = (const float*)d_in[5];
    const float* wvre = (const float*)d_in[6];
    const float* wvim = (const float*)d_in[7];
    const float* wore = (const float*)d_in[8];
    const float* woim = (const float*)d_in[9];
    float* out = (float*)d_out;

    // workspace layout (~160 MB)
    char* p = (char*)d_ws;
    const size_t QK = (size_t)B_DIM * H_DIM * S_DIM * M_DIM;   // 8.39M
    const size_t VS = (size_t)B_DIM * H_DIM * S_DIM * V_DIM;   // 4.19M
    const size_t SBE = (size_t)S_DIM * B_DIM * E_DIM;          // 4.19M
    unsigned short* qrw = (unsigned short*)p;  p += QK * 2;
    unsigned short* qiw = (unsigned short*)p;  p += QK * 2;
    unsigned short* krw = (unsigned short*)p;  p += QK * 2;
    unsigned short* kiw = (unsigned short*)p;  p += QK * 2;
    unsigned short* vrw = (unsigned short*)p;  p += VS * 2;
    unsigned short* viw = (unsigned short*)p;  p += VS * 2;
    unsigned short* vrt = (unsigned short*)p;  p += VS * 2;
    unsigned short* vit = (unsigned short*)p;  p += VS * 2;
    unsigned short* updre = (unsigned short*)p; p += SBE * 2;
    unsigned short* updim = (unsigned short*)p; p += SBE * 2;
    unsigned short* xbre  = (unsigned short*)p; p += SBE * 2;
    unsigned short* xbim  = (unsigned short*)p; p += SBE * 2;
    unsigned short* wbre  = (unsigned short*)p; p += (size_t)5120 * E_DIM * 2;
    unsigned short* wbim  = (unsigned short*)p; p += (size_t)5120 * E_DIM * 2;
    unsigned short* wtre  = (unsigned short*)p; p += (size_t)E_DIM * E_DIM * 2;
    unsigned short* wtim  = (unsigned short*)p; p += (size_t)E_DIM * E_DIM * 2;

    // bf16 conversion passes
    convert_pair<<<4096, 256, 0, stream>>>(xre, xim, xbre, xbim, 1048576);
    convert_pair<<<2048, 256, 0, stream>>>(wqre, wqim, wbre, wbim, 524288);
    convert_pair<<<2048, 256, 0, stream>>>(wkre, wkim, wbre + 2048*1024, wbim + 2048*1024, 524288);
    convert_pair<<<1024, 256, 0, stream>>>(wvre, wvim, wbre + 4096*1024, wbim + 4096*1024, 262144);
    transpose_wo<<<dim3(32, 32), 256, 0, stream>>>(wore, woim, wtre, wtim);

    // QKV projection (bf16 MFMA) -> separated planes
    cgemm<0><<<dim3(32, 80), 256, 0, stream>>>(xbre, xbim, wbre, wbim,
                                               qrw, qiw, krw, kiw, vrw, viw,
                                               nullptr, nullptr, nullptr);
    // V -> V^T planes
    vtrans<<<dim3(16, 64), 256, 0, stream>>>(vrw, viw, vrt, vit);
    // MFMA flash attention
    attn_mfma<<<dim3(16, 64), 256, 0, stream>>>(qrw, qiw, krw, kiw, vrt, vit, updre, updim);
    // output projection + residual (plain stores)
    cgemm<1><<<dim3(32, 16), 256, 0, stream>>>(updre, updim, wtre, wtim,
                                               nullptr, nullptr, nullptr, nullptr, nullptr, nullptr,
                                               xre, xim, out);
}

// Round 7
// 507.237 us; speedup vs baseline: 1.5215x; 1.0005x over previous
//
#include <hip/hip_runtime.h>
#include <math.h>

#define S_DIM 1024
#define B_DIM 4
#define E_DIM 1024
#define H_DIM 16
#define M_DIM 128
#define V_DIM 64

typedef __attribute__((ext_vector_type(8))) short short8;
typedef __attribute__((ext_vector_type(4))) float f32x4;
typedef __attribute__((ext_vector_type(4))) int int4v;

__device__ __forceinline__ unsigned short f2bf(float f) {
    union { float f; unsigned u; } v; v.f = f;
    unsigned r = v.u + 0x7FFFu + ((v.u >> 16) & 1u);   // round-to-nearest-even
    return (unsigned short)(r >> 16);
}

__device__ __forceinline__ void async16(const unsigned short* g, unsigned short* l) {
    __builtin_amdgcn_global_load_lds(
        (const __attribute__((address_space(1))) void*)g,
        (__attribute__((address_space(3))) void*)l,
        16, 0, 0);
}

// ---------------- convert: fp32 (re,im) -> bf16 arrays ----------------
__global__ __launch_bounds__(256) void convert_pair(
    const float* __restrict__ re, const float* __restrict__ im,
    unsigned short* __restrict__ dre, unsigned short* __restrict__ dim_, int n4)
{
    int i = blockIdx.x * 256 + threadIdx.x;
    if (i >= n4) return;
    float4 r = ((const float4*)re)[i];
    float4 m = ((const float4*)im)[i];
    ushort4 ro, mo;
    ro.x = f2bf(r.x); ro.y = f2bf(r.y); ro.z = f2bf(r.z); ro.w = f2bf(r.w);
    mo.x = f2bf(m.x); mo.y = f2bf(m.y); mo.z = f2bf(m.z); mo.w = f2bf(m.w);
    ((ushort4*)dre)[i] = ro;
    ((ushort4*)dim_)[i] = mo;
}

// wo (e,f) -> woT (f,e) bf16
__global__ __launch_bounds__(256) void transpose_wo(
    const float* __restrict__ wore, const float* __restrict__ woim,
    unsigned short* __restrict__ wtre, unsigned short* __restrict__ wtim)
{
    __shared__ float tr[32][33], ti[32][33];
    const int bx = blockIdx.x * 32;   // e range
    const int by = blockIdx.y * 32;   // f range
    const int tx = threadIdx.x & 31, ty = threadIdx.x >> 5;
    for (int i = ty; i < 32; i += 8) {
        tr[i][tx] = wore[(bx + i) * E_DIM + by + tx];
        ti[i][tx] = woim[(bx + i) * E_DIM + by + tx];
    }
    __syncthreads();
    for (int i = ty; i < 32; i += 8) {
        wtre[(by + i) * E_DIM + bx + tx] = f2bf(tr[tx][i]);
        wtim[(by + i) * E_DIM + bx + tx] = f2bf(ti[tx][i]);
    }
}

// v planes [bh][t][64] -> v^T planes [bh][v][1024]
__global__ __launch_bounds__(256) void vtrans(
    const unsigned short* __restrict__ vrp, const unsigned short* __restrict__ vip,
    unsigned short* __restrict__ vrt, unsigned short* __restrict__ vit)
{
    __shared__ unsigned short tl[2][64][66];
    const int tid = threadIdx.x;
    const int t0 = blockIdx.x * 64;
    const int bh = blockIdx.y;
    #pragma unroll
    for (int pl = 0; pl < 2; ++pl) {
        const unsigned short* src = pl ? vip : vrp;
        #pragma unroll
        for (int p = 0; p < 2; ++p) {
            const int row = p * 32 + (tid >> 3);
            const int col = (tid & 7) * 8;
            short8 d = *(const short8*)&src[((size_t)bh * S_DIM + t0 + row) * V_DIM + col];
            #pragma unroll
            for (int j = 0; j < 8; ++j) tl[pl][row][col + j] = (unsigned short)d[j];
        }
    }
    __syncthreads();
    #pragma unroll
    for (int pl = 0; pl < 2; ++pl) {
        unsigned short* dst = pl ? vit : vrt;
        #pragma unroll
        for (int p = 0; p < 2; ++p) {
            const int v = p * 32 + (tid >> 3);
            const int tc = (tid & 7) * 8;
            short8 d;
            #pragma unroll
            for (int j = 0; j < 8; ++j) d[j] = (short)tl[pl][tc + j][v];
            *(short8*)&dst[((size_t)bh * V_DIM + v) * S_DIM + t0 + tc] = d;
        }
    }
}

// ---------------- complex bf16 MFMA GEMM: C = A * B^T ----------------
// Block tile 128x64, 2x2 waves of 64x32 -> acc in AGPRs (64), ~68 arch VGPR,
// 48 KB LDS -> 3 blocks/CU (measured r6: MfmaUtil 45%, no spill).
// MODE 0: Mr=4096 (s,b), Nc=5120 (q|k|v) -> bf16 planes qr/qi/kr/ki/vr/vi
// MODE 1: Mr=4096, Nc=1024 -> out = acc + x (fp32, stacked re/im), plain stores
template<int MODE>
__global__ __launch_bounds__(256, 3) void cgemm(
    const unsigned short* __restrict__ Are, const unsigned short* __restrict__ Aim,
    const unsigned short* __restrict__ Bre, const unsigned short* __restrict__ Bim,
    unsigned short* __restrict__ qrp, unsigned short* __restrict__ qip,
    unsigned short* __restrict__ krp, unsigned short* __restrict__ kip,
    unsigned short* __restrict__ vrp, unsigned short* __restrict__ vip,
    const float* __restrict__ xre, const float* __restrict__ xim,
    float* __restrict__ out)
{
    // 48 KB: 2 kk-halves x (Ar[128][32] | Ai[128][32] | Br[64][32] | Bi[64][32])
    __shared__ unsigned short lds[24576];
    const int tid  = threadIdx.x;
    const int wave = tid >> 6;
    const int lane = tid & 63;
    const int r0 = blockIdx.x * 128;
    const int j0 = blockIdx.y * 64;
    const int wm = (wave >> 1) * 64;   // m half
    const int wn = (wave & 1) * 32;    // n half

    f32x4 accre[4][2], accim[4][2];
    #pragma unroll
    for (int i = 0; i < 4; ++i)
        #pragma unroll
        for (int j = 0; j < 2; ++j) {
            accre[i][j] = (f32x4){0.f, 0.f, 0.f, 0.f};
            accim[i][j] = (f32x4){0.f, 0.f, 0.f, 0.f};
        }

    const int srow = lane >> 2;          // staging: 4 lanes per 64B row
    const int scol = (lane & 3) * 8;
    const int fr = lane & 15;            // frag: m/n index
    const int fk = (lane >> 4) * 8;      // frag: k offset

    for (int k0 = 0; k0 < E_DIM; k0 += 64) {
        __syncthreads();
        #pragma unroll
        for (int kk = 0; kk < 2; ++kk) {
            const int kb = kk * 12288;
            const int kg = k0 + kk * 32;
            #pragma unroll
            for (int c = 0; c < 2; ++c) {
                const int row0 = wave * 32 + c * 16;
                const int g = (r0 + row0 + srow) * E_DIM + kg + scol;
                async16(Are + g, &lds[kb + row0 * 32]);
                async16(Aim + g, &lds[kb + 4096 + row0 * 32]);
            }
            {
                const int row0 = wave * 16;
                const int g = (j0 + row0 + srow) * E_DIM + kg + scol;
                async16(Bre + g, &lds[kb + 8192 + row0 * 32]);
                async16(Bim + g, &lds[kb + 10240 + row0 * 32]);
            }
        }
        __syncthreads();

        #pragma unroll
        for (int kk = 0; kk < 2; ++kk) {
            const int kb = kk * 12288;
            short8 ar[4], ai[4];
            #pragma unroll
            for (int im = 0; im < 4; ++im) {
                const int row = wm + im * 16 + fr;
                ar[im] = *(const short8*)&lds[kb + row * 32 + fk];
                ai[im] = *(const short8*)&lds[kb + 4096 + row * 32 + fk];
            }
            #pragma unroll
            for (int jn = 0; jn < 2; ++jn) {
                const int row = wn + jn * 16 + fr;
                const short8 br = *(const short8*)&lds[kb + 8192 + row * 32 + fk];
                const short8 bi = *(const short8*)&lds[kb + 10240 + row * 32 + fk];
                int4v t = *(int4v*)&bi;
                t = t ^ (int)0x80008000;       // bin = -bi (transient)
                const short8 bin = *(short8*)&t;
                #pragma unroll
                for (int im = 0; im < 4; ++im) {
                    accre[im][jn] = __builtin_amdgcn_mfma_f32_16x16x32_bf16(ar[im], br,  accre[im][jn], 0, 0, 0);
                    accre[im][jn] = __builtin_amdgcn_mfma_f32_16x16x32_bf16(ai[im], bin, accre[im][jn], 0, 0, 0);
                    accim[im][jn] = __builtin_amdgcn_mfma_f32_16x16x32_bf16(ar[im], bi,  accim[im][jn], 0, 0, 0);
                    accim[im][jn] = __builtin_amdgcn_mfma_f32_16x16x32_bf16(ai[im], br,  accim[im][jn], 0, 0, 0);
                }
            }
        }
    }

    // epilogue: D row = (lane>>4)*4+reg, col = lane&15  [measured m89/m91]
    #pragma unroll
    for (int im = 0; im < 4; ++im) {
        #pragma unroll
        for (int reg = 0; reg < 4; ++reg) {
            const int r = r0 + wm + im * 16 + (lane >> 4) * 4 + reg;
            #pragma unroll
            for (int jn = 0; jn < 2; ++jn) {
                const int j = j0 + wn + jn * 16 + fr;
                const float vr = accre[im][jn][reg];
                const float vi = accim[im][jn][reg];
                if (MODE == 0) {
                    const int s = r >> 2, b = r & 3;   // r = s*B + b
                    if (j < 2048) {
                        const int h = j >> 7, m = j & 127;
                        const size_t off = ((size_t)(b * H_DIM + h) * S_DIM + s) * M_DIM + m;
                        qrp[off] = f2bf(vr); qip[off] = f2bf(vi);
                    } else if (j < 4096) {
                        const int jl = j - 2048, h = jl >> 7, m = jl & 127;
                        const size_t off = ((size_t)(b * H_DIM + h) * S_DIM + s) * M_DIM + m;
                        krp[off] = f2bf(vr); kip[off] = f2bf(vi);
                    } else {
                        const int jl = j - 4096, h = jl >> 6, vv = jl & 63;
                        const size_t off = ((size_t)(b * H_DIM + h) * S_DIM + s) * V_DIM + vv;
                        vrp[off] = f2bf(vr); vip[off] = f2bf(vi);
                    }
                } else {
                    const int idx = r * E_DIM + j;
                    out[idx] = vr + xre[idx];
                    out[S_DIM * B_DIM * E_DIM + idx] = vi + xim[idx];
                }
            }
        }
    }
}

// ---------------- K2: MFMA flash attention, S^T orientation ----------------
// block = one (b,h) x 64 q; 4 waves x 16 q-cols; K-tile 64.
// S^T = K*Q^T: C col = q = lane&15 -> t-reduction is in-lane + 2 quad shfls;
// m/l/alpha are per-lane scalars. O accumulates as O^T[v][q] (col=q).
__global__ __launch_bounds__(256, 2) void attn_mfma(
    const unsigned short* __restrict__ qr, const unsigned short* __restrict__ qi,
    const unsigned short* __restrict__ kr, const unsigned short* __restrict__ ki,
    const unsigned short* __restrict__ vrt, const unsigned short* __restrict__ vit,
    unsigned short* __restrict__ updre, unsigned short* __restrict__ updim)
{
    __shared__ __align__(16) unsigned short Ks[2][64][136];  // K tile [plane][t][m] (Q staged here first)
    __shared__ __align__(16) unsigned short Vs[2][64][72];   // V^T tile [plane][v][t]
    __shared__ __align__(16) unsigned short Ps[4][16][80];   // per-wave P [q][t], pitch 80: 2-way banks

    const int tid  = threadIdx.x;
    const int wave = tid >> 6;
    const int lane = tid & 63;
    const int qt = (int)gridDim.x - 1 - blockIdx.x;  // long blocks launch first
    const int bh = blockIdx.y;
    const int q0 = qt * 64;
    const size_t base_qk = (size_t)bh * S_DIM * M_DIM;
    const size_t base_v  = (size_t)bh * V_DIM * S_DIM;

    const int fr = lane & 15;        // q col (QK/PV); A-frag row index
    const int fg = lane >> 4;        // quad 0..3
    const int fk = fg * 8;           // frag k offset (bf16)

    // staging coords
    const int krow = tid >> 4, kcol = (tid & 15) * 8;   // K: 16 rows/pass
    const int vrow = tid >> 3, vcol = (tid & 7) * 8;    // V: 32 rows/pass

    // ---- stage Q tile into Ks, extract per-wave B-frags (Q[q=fr][m]) ----
    #pragma unroll
    for (int pl = 0; pl < 2; ++pl) {
        const unsigned short* src = pl ? qi : qr;
        #pragma unroll
        for (int p = 0; p < 4; ++p)
            *(short8*)&Ks[pl][p * 16 + krow][kcol] =
                *(const short8*)&src[base_qk + (size_t)(q0 + p * 16 + krow) * M_DIM + kcol];
    }
    __syncthreads();
    short8 Bqr[4], Bqi[4];
    {
        const int qrow = wave * 16 + fr;
        #pragma unroll
        for (int ks = 0; ks < 4; ++ks) {
            Bqr[ks] = *(const short8*)&Ks[0][qrow][ks * 32 + fk];
            Bqi[ks] = *(const short8*)&Ks[1][qrow][ks * 32 + fk];
        }
    }

    f32x4 Ore[4], Oim[4];   // O^T[v = vt*16+fg*4+reg][q = fr]
    #pragma unroll
    for (int vt = 0; vt < 4; ++vt) {
        Ore[vt] = (f32x4){0.f, 0.f, 0.f, 0.f};
        Oim[vt] = (f32x4){0.f, 0.f, 0.f, 0.f};
    }
    float mrun = -INFINITY, lrun = 0.f;

    const float scale = 0.088388347648318447f;  // 1/sqrt(128)
    const int qglob = q0 + wave * 16 + fr;      // this lane's q

    // ---- prefetch tile t0=0 into registers ----
    short8 pk[2][4], pv[2][2];
    #pragma unroll
    for (int pl = 0; pl < 2; ++pl) {
        const unsigned short* src = pl ? ki : kr;
        #pragma unroll
        for (int p = 0; p < 4; ++p)
            pk[pl][p] = *(const short8*)&src[base_qk + (size_t)(p * 16 + krow) * M_DIM + kcol];
    }
    #pragma unroll
    for (int pl = 0; pl < 2; ++pl) {
        const unsigned short* src = pl ? vit : vrt;
        #pragma unroll
        for (int p = 0; p < 2; ++p)
            pv[pl][p] = *(const short8*)&src[base_v + (size_t)(p * 32 + vrow) * S_DIM + vcol];
    }

    for (int t0 = 0; t0 <= q0; t0 += 64) {
        __syncthreads();   // prior readers of Ks/Vs done (iter0: Q frags extracted)
        // ---- commit prefetched K/V tile to LDS ----
        #pragma unroll
        for (int pl = 0; pl < 2; ++pl) {
            #pragma unroll
            for (int p = 0; p < 4; ++p)
                *(short8*)&Ks[pl][p * 16 + krow][kcol] = pk[pl][p];
            #pragma unroll
            for (int p = 0; p < 2; ++p)
                *(short8*)&Vs[pl][p * 32 + vrow][vcol] = pv[pl][p];
        }
        __syncthreads();

        // ---- issue next tile's global loads (consumed next iteration) ----
        if (t0 + 64 <= q0) {
            const int tn = t0 + 64;
            #pragma unroll
            for (int pl = 0; pl < 2; ++pl) {
                const unsigned short* src = pl ? ki : kr;
                #pragma unroll
                for (int p = 0; p < 4; ++p)
                    pk[pl][p] = *(const short8*)&src[base_qk + (size_t)(tn + p * 16 + krow) * M_DIM + kcol];
            }
            #pragma unroll
            for (int pl = 0; pl < 2; ++pl) {
                const unsigned short* src = pl ? vit : vrt;
                #pragma unroll
                for (int p = 0; p < 2; ++p)
                    pv[pl][p] = *(const short8*)&src[base_v + (size_t)(p * 32 + vrow) * S_DIM + tn + vcol];
            }
        }

        // ---- S^T = K Q^T (complex): A = K frags, B = Q frags ----
        f32x4 Sre[4], Sim[4];   // t = tt*16 + fg*4 + reg, q = fr
        #pragma unroll
        for (int tt = 0; tt < 4; ++tt) {
            Sre[tt] = (f32x4){0.f, 0.f, 0.f, 0.f};
            Sim[tt] = (f32x4){0.f, 0.f, 0.f, 0.f};
            const int trow = tt * 16 + fr;
            #pragma unroll
            for (int ks = 0; ks < 4; ++ks) {
                const short8 Akr = *(const short8*)&Ks[0][trow][ks * 32 + fk];
                const short8 Aki = *(const short8*)&Ks[1][trow][ks * 32 + fk];
                int4v t = *(int4v*)&Aki;
                t = t ^ (int)0x80008000;       // -Ki (transient)
                const short8 Akin = *(short8*)&t;
                Sre[tt] = __builtin_amdgcn_mfma_f32_16x16x32_bf16(Akr,  Bqr[ks], Sre[tt], 0, 0, 0);
                Sre[tt] = __builtin_amdgcn_mfma_f32_16x16x32_bf16(Akin, Bqi[ks], Sre[tt], 0, 0, 0);
                Sim[tt] = __builtin_amdgcn_mfma_f32_16x16x32_bf16(Akr,  Bqi[ks], Sim[tt], 0, 0, 0);
                Sim[tt] = __builtin_amdgcn_mfma_f32_16x16x32_bf16(Aki,  Bqr[ks], Sim[tt], 0, 0, 0);
            }
        }

        // ---- amplitude + causal mask; t-reduction in-lane + 2 quad shfls ----
        float amp[4][4];
        float rowmax = -INFINITY;
        #pragma unroll
        for (int tt = 0; tt < 4; ++tt) {
            #pragma unroll
            for (int r = 0; r < 4; ++r) {
                const int tg = t0 + tt * 16 + fg * 4 + r;
                const float re = Sre[tt][r], im = Sim[tt][r];
                const float a = sqrtf(re * re + im * im) * scale;
                const float av = (tg > qglob) ? -INFINITY : a;
                amp[tt][r] = av;
                rowmax = fmaxf(rowmax, av);
            }
        }
        rowmax = fmaxf(rowmax, __shfl_xor(rowmax, 16));
        rowmax = fmaxf(rowmax, __shfl_xor(rowmax, 32));
        const float nm = fmaxf(mrun, rowmax);
        const float alpha = __expf(mrun - nm);
        mrun = nm;
        float psum = 0.f;
        #pragma unroll
        for (int tt = 0; tt < 4; ++tt) {
            #pragma unroll
            for (int r = 0; r < 4; ++r) {
                const float p = __expf(amp[tt][r] - nm);
                psum += p;
                Ps[wave][fr][tt * 16 + fg * 4 + r] = f2bf(p);
            }
        }
        psum += __shfl_xor(psum, 16);
        psum += __shfl_xor(psum, 32);
        lrun = lrun * alpha + psum;

        #pragma unroll
        for (int vt = 0; vt < 4; ++vt)
            #pragma unroll
            for (int r = 0; r < 4; ++r) { Ore[vt][r] *= alpha; Oim[vt][r] *= alpha; }

        // ---- O^T += V^T P^T : A = V^T frags, B = P frags (per-wave LDS) ----
        const short8 Bp0 = *(const short8*)&Ps[wave][fr][fk];
        const short8 Bp1 = *(const short8*)&Ps[wave][fr][32 + fk];
        #pragma unroll
        for (int vt = 0; vt < 4; ++vt) {
            const int vr2 = vt * 16 + fr;
            const short8 Ar0 = *(const short8*)&Vs[0][vr2][fk];
            const short8 Ar1 = *(const short8*)&Vs[0][vr2][32 + fk];
            const short8 Ai0 = *(const short8*)&Vs[1][vr2][fk];
            const short8 Ai1 = *(const short8*)&Vs[1][vr2][32 + fk];
            Ore[vt] = __builtin_amdgcn_mfma_f32_16x16x32_bf16(Ar0, Bp0, Ore[vt], 0, 0, 0);
            Ore[vt] = __builtin_amdgcn_mfma_f32_16x16x32_bf16(Ar1, Bp1, Ore[vt], 0, 0, 0);
            Oim[vt] = __builtin_amdgcn_mfma_f32_16x16x32_bf16(Ai0, Bp0, Oim[vt], 0, 0, 0);
            Oim[vt] = __builtin_amdgcn_mfma_f32_16x16x32_bf16(Ai1, Bp1, Oim[vt], 0, 0, 0);
        }
    }

    // ---- epilogue: lane owns q = qglob; v = vt*16 + fg*4 + reg ----
    const int b = bh >> 4, h = bh & 15;
    const float inv = 1.0f / lrun;
    const size_t base = ((size_t)(qglob * B_DIM + b)) * E_DIM + h * V_DIM;
    #pragma unroll
    for (int vt = 0; vt < 4; ++vt) {
        ushort4 pr, pi;
        pr.x = f2bf(Ore[vt][0] * inv); pr.y = f2bf(Ore[vt][1] * inv);
        pr.z = f2bf(Ore[vt][2] * inv); pr.w = f2bf(Ore[vt][3] * inv);
        pi.x = f2bf(Oim[vt][0] * inv); pi.y = f2bf(Oim[vt][1] * inv);
        pi.z = f2bf(Oim[vt][2] * inv); pi.w = f2bf(Oim[vt][3] * inv);
        *(ushort4*)&updre[base + vt * 16 + fg * 4] = pr;
        *(ushort4*)&updim[base + vt * 16 + fg * 4] = pi;
    }
}

extern "C" void kernel_launch(void* const* d_in, const int* in_sizes, int n_in,
                              void* d_out, int out_size, void* d_ws, size_t ws_size,
                              hipStream_t stream) {
    const float* xre  = (const float*)d_in[0];
    const float* xim  = (const float*)d_in[1];
    const float* wqre = (const float*)d_in[2];
    const float* wqim = (const float*)d_in[3];
    const float* wkre = (const float*)d_in[4];
    const float* wkim = (const float*)d_in[5];
    const float* wvre = (const float*)d_in[6];
    const float* wvim = (const float*)d_in[7];
    const float* wore = (const float*)d_in[8];
    const float* woim = (const float*)d_in[9];
    float* out = (float*)d_out;

    // workspace layout (~160 MB)
    char* p = (char*)d_ws;
    const size_t QK = (size_t)B_DIM * H_DIM * S_DIM * M_DIM;   // 8.39M
    const size_t VS = (size_t)B_DIM * H_DIM * S_DIM * V_DIM;   // 4.19M
    const size_t SBE = (size_t)S_DIM * B_DIM * E_DIM;          // 4.19M
    unsigned short* qrw = (unsigned short*)p;  p += QK * 2;
    unsigned short* qiw = (unsigned short*)p;  p += QK * 2;
    unsigned short* krw = (unsigned short*)p;  p += QK * 2;
    unsigned short* kiw = (unsigned short*)p;  p += QK * 2;
    unsigned short* vrw = (unsigned short*)p;  p += VS * 2;
    unsigned short* viw = (unsigned short*)p;  p += VS * 2;
    unsigned short* vrt = (unsigned short*)p;  p += VS * 2;
    unsigned short* vit = (unsigned short*)p;  p += VS * 2;
    unsigned short* updre = (unsigned short*)p; p += SBE * 2;
    unsigned short* updim = (unsigned short*)p; p += SBE * 2;
    unsigned short* xbre  = (unsigned short*)p; p += SBE * 2;
    unsigned short* xbim  = (unsigned short*)p; p += SBE * 2;
    unsigned short* wbre  = (unsigned short*)p; p += (size_t)5120 * E_DIM * 2;
    unsigned short* wbim  = (unsigned short*)p; p += (size_t)5120 * E_DIM * 2;
    unsigned short* wtre  = (unsigned short*)p; p += (size_t)E_DIM * E_DIM * 2;
    unsigned short* wtim  = (unsigned short*)p; p += (size_t)E_DIM * E_DIM * 2;

    // bf16 conversion passes
    convert_pair<<<4096, 256, 0, stream>>>(xre, xim, xbre, xbim, 1048576);
    convert_pair<<<2048, 256, 0, stream>>>(wqre, wqim, wbre, wbim, 524288);
    convert_pair<<<2048, 256, 0, stream>>>(wkre, wkim, wbre + 2048*1024, wbim + 2048*1024, 524288);
    convert_pair<<<1024, 256, 0, stream>>>(wvre, wvim, wbre + 4096*1024, wbim + 4096*1024, 262144);
    transpose_wo<<<dim3(32, 32), 256, 0, stream>>>(wore, woim, wtre, wtim);

    // QKV projection (bf16 MFMA) -> separated planes
    cgemm<0><<<dim3(32, 80), 256, 0, stream>>>(xbre, xbim, wbre, wbim,
                                               qrw, qiw, krw, kiw, vrw, viw,
                                               nullptr, nullptr, nullptr);
    // V -> V^T planes
    vtrans<<<dim3(16, 64), 256, 0, stream>>>(vrw, viw, vrt, vit);
    // MFMA flash attention (S^T orientation)
    attn_mfma<<<dim3(16, 64), 256, 0, stream>>>(qrw, qiw, krw, kiw, vrt, vit, updre, updim);
    // output projection + residual (plain stores)
    cgemm<1><<<dim3(32, 16), 256, 0, stream>>>(updre, updim, wtre, wtim,
                                               nullptr, nullptr, nullptr, nullptr, nullptr, nullptr,
                                               xre, xim, out);
}